// Round 1
// baseline (7256.881 us; speedup 1.0000x reference)
//
#include <hip/hip_runtime.h>
#include <math.h>

namespace {

constexpr int BATCH = 2;
constexpr int NTOK  = 8192;    // tokens per batch (T*H*W)
constexpr int MROWS = 16384;   // BATCH*NTOK
constexpr int C     = 512;
constexpr int GH    = 8;
constexpr int DH    = 32;
constexpr int WIN   = 64;
constexpr int NW    = 128;     // NTOK/WIN
constexpr int FF    = 1024;
constexpr int NBF   = 110;     // int(32*ln(32))

constexpr float F_DN     = 0.42044820762685725f;   // 32^-0.25
constexpr float F_RNORM  = 0.09534625892455924f;   // 110^-0.5
constexpr float F_LSCALE = 0.17677669529663687f;   // 32^-0.5

__device__ __forceinline__ unsigned ford(float f){
  unsigned u = __float_as_uint(f);
  return (u & 0x80000000u) ? ~u : (u | 0x80000000u);
}
__device__ __forceinline__ float forde(unsigned u){
  return (u & 0x80000000u) ? __uint_as_float(u ^ 0x80000000u) : __uint_as_float(~u);
}

__global__ void k_tables(float* __restrict__ cost, float* __restrict__ sint){
  int idx = blockIdx.x*256 + threadIdx.x;
  if (idx >= NTOK*16) return;
  int pos = idx >> 4, f = idx & 15;
  float inv = powf(10000.f, -(float)f/16.f);
  float ang = (float)pos * inv;
  cost[idx] = cosf(ang);
  sint[idx] = sinf(ang);
}

__global__ void k_copy(const float4* __restrict__ s, float4* __restrict__ d, int n){
  int i = blockIdx.x*256 + threadIdx.x;
  if (i < n) d[i] = s[i];
}

__global__ void k_zstab(unsigned* s){ if (threadIdx.x < 16) s[threadIdx.x] = 0u; }

__global__ __launch_bounds__(256) void k_ln(const float* __restrict__ x, const float* __restrict__ g,
                     const float* __restrict__ b, float* __restrict__ y){
  int row = blockIdx.x, t = threadIdx.x;
  const float* xr = x + (size_t)row*C;
  float2 v = *(const float2*)(xr + 2*t);
  float s = v.x + v.y, ss = v.x*v.x + v.y*v.y;
  #pragma unroll
  for (int o = 32; o; o >>= 1){ s += __shfl_down(s, o); ss += __shfl_down(ss, o); }
  __shared__ float rs[4], rss[4];
  int wv = t >> 6, ln = t & 63;
  if (ln == 0){ rs[wv] = s; rss[wv] = ss; }
  __syncthreads();
  float S = rs[0]+rs[1]+rs[2]+rs[3], SS = rss[0]+rss[1]+rss[2]+rss[3];
  float mean = S * (1.f/C);
  float var  = SS * (1.f/C) - mean*mean;
  float rstd = rsqrtf(var + 1e-5f);
  float2 gg = *(const float2*)(g + 2*t);
  float2 bb = *(const float2*)(b + 2*t);
  float2 out;
  out.x = (v.x - mean)*rstd*gg.x + bb.x;
  out.y = (v.y - mean)*rstd*gg.y + bb.y;
  *(float2*)(y + (size_t)row*C + 2*t) = out;
}

// out = ACT(A@W + bias) (+ res).  A:(M,K) W:(K,N) row-major.  M%128==0, N%128==0, K%8==0.
template<int ACT>
__global__ __launch_bounds__(256) void k_gemm(const float* __restrict__ A, const float* __restrict__ W,
      const float* __restrict__ bias, const float* __restrict__ res, float* __restrict__ out,
      int Md, int Nd, int Kd){
  constexpr int BM=128, BN=128, BK=8;
  __shared__ float As[BK][BM];
  __shared__ float Bs[BK][BN];
  int tid = threadIdx.x;
  int tx = tid & 15, ty = tid >> 4;
  int row0 = blockIdx.y*BM, col0 = blockIdx.x*BN;
  float acc[8][8] = {};
  int ar = tid >> 1, ac = (tid & 1)*4;
  int br = tid >> 5, bc = (tid & 31)*4;
  const float* Ap = A + (size_t)(row0+ar)*Kd + ac;
  const float* Wp = W + (size_t)br*Nd + col0 + bc;
  for (int k0 = 0; k0 < Kd; k0 += BK){
    float4 av = *(const float4*)(Ap + k0);
    float4 bv = *(const float4*)(Wp + (size_t)k0*Nd);
    __syncthreads();
    As[ac+0][ar]=av.x; As[ac+1][ar]=av.y; As[ac+2][ar]=av.z; As[ac+3][ar]=av.w;
    *(float4*)(&Bs[br][bc]) = bv;
    __syncthreads();
    #pragma unroll
    for (int kk = 0; kk < BK; kk++){
      float af[8], bf[8];
      *(float4*)(af)   = *(const float4*)(&As[kk][ty*8]);
      *(float4*)(af+4) = *(const float4*)(&As[kk][ty*8+4]);
      *(float4*)(bf)   = *(const float4*)(&Bs[kk][tx*8]);
      *(float4*)(bf+4) = *(const float4*)(&Bs[kk][tx*8+4]);
      #pragma unroll
      for (int i = 0; i < 8; i++)
        #pragma unroll
        for (int j = 0; j < 8; j++)
          acc[i][j] += af[i]*bf[j];
    }
  }
  #pragma unroll
  for (int i = 0; i < 8; i++){
    int r = row0 + ty*8 + i;
    const float* rr = res ? res + (size_t)r*Nd : nullptr;
    float* orow = out + (size_t)r*Nd;
    #pragma unroll
    for (int j = 0; j < 8; j++){
      int c = col0 + tx*8 + j;
      float vv = acc[i][j] + bias[c];
      if (ACT == 1) vv = 0.5f*vv*(1.f + erff(vv*0.7071067811865476f));
      if (res) vv += rr[c];
      orow[c] = vv;
    }
  }
}

// RoPE in place on local-head channels [256,512) of q and k.
__global__ void k_rope(float* __restrict__ q, float* __restrict__ k,
                       const float* __restrict__ cost, const float* __restrict__ sint){
  int idx = blockIdx.x*256 + threadIdx.x;
  if (idx >= MROWS*128) return;
  int r = idx >> 7, p = idx & 127;
  int head = p >> 4, d = p & 15;
  int pos = r & (NTOK-1);
  float cv = cost[pos*16+d], sv = sint[pos*16+d];
  size_t base = (size_t)r*C + 256 + head*32 + d;
  float a = q[base], b2 = q[base+16];
  q[base]    = a*cv - b2*sv;
  q[base+16] = b2*cv + a*sv;
  float ka = k[base], kb = k[base+16];
  k[base]    = ka*cv - kb*sv;
  k[base+16] = kb*cv + ka*sv;
}

// Performer K pass 1: per-row diag, global (per b,h) stab via ordered atomicMax.
__global__ __launch_bounds__(128) void k_kstab(const float* __restrict__ k, const float* __restrict__ proj,
        float* __restrict__ diag, unsigned* __restrict__ stab){
  int row = blockIdx.x;               // bh*NTOK + i
  int bh = row >> 13, i = row & (NTOK-1);
  int b = bh >> 3, h = bh & 7;
  const float* kr = k + (size_t)(b*NTOK + i)*C + h*DH;
  __shared__ float kl[DH];
  __shared__ float red[128];
  int t = threadIdx.x;
  if (t < DH) kl[t] = kr[t];
  __syncthreads();
  float dd = -1e30f;
  if (t < NBF){
    const float* pm = proj + t*DH;
    float a = 0.f;
    #pragma unroll
    for (int d = 0; d < DH; d++) a += kl[d]*pm[d];
    dd = a * F_DN;
  }
  if (t == 0){
    float sq = 0.f;
    #pragma unroll
    for (int d = 0; d < DH; d++) sq += kl[d]*kl[d];
    diag[row] = 0.5f*F_DN*F_DN*sq;
  }
  red[t] = dd;
  __syncthreads();
  #pragma unroll
  for (int o = 64; o; o >>= 1){
    if (t < o) red[t] = fmaxf(red[t], red[t+o]);
    __syncthreads();
  }
  if (t == 0) atomicMax(&stab[bh], ford(red[0]));
}

// Performer K pass 2: recompute dd -> kp, accumulate ksum[m] and ctx[m][d].
__global__ __launch_bounds__(256) void k_ctx(const float* __restrict__ k, const float* __restrict__ v,
        const float* __restrict__ proj, const float* __restrict__ diag, const unsigned* __restrict__ stab,
        float* __restrict__ ctx, float* __restrict__ ksum){
  int blk = blockIdx.x;
  int m = blk % NBF, bh = blk / NBF;
  int b = bh >> 3, h = bh & 7;
  __shared__ float pm[DH];
  int t = threadIdx.x;
  if (t < DH) pm[t] = proj[m*DH + t] * F_DN;
  __syncthreads();
  float stf = forde(stab[bh]);
  float acc[DH] = {};
  float ks = 0.f;
  for (int i = t; i < NTOK; i += 256){
    const float* kr = k + (size_t)(b*NTOK + i)*C + h*DH;
    float ddv = 0.f;
    #pragma unroll
    for (int d = 0; d < DH; d++) ddv += kr[d]*pm[d];
    float kp = F_RNORM*(expf(ddv - diag[bh*NTOK + i] - stf) + 1e-4f);
    ks += kp;
    const float* vr = v + (size_t)(b*NTOK + i)*C + h*DH;
    #pragma unroll
    for (int d = 0; d < DH; d++) acc[d] += kp*vr[d];
  }
  #pragma unroll
  for (int o = 32; o; o >>= 1){
    ks += __shfl_down(ks, o);
    #pragma unroll
    for (int d = 0; d < DH; d++) acc[d] += __shfl_down(acc[d], o);
  }
  __shared__ float wacc[4][DH];
  __shared__ float wks[4];
  int wv = t >> 6, ln = t & 63;
  if (ln == 0){
    wks[wv] = ks;
    #pragma unroll
    for (int d = 0; d < DH; d++) wacc[wv][d] = acc[d];
  }
  __syncthreads();
  if (t == 0) ksum[bh*NBF + m] = wks[0]+wks[1]+wks[2]+wks[3];
  if (t < DH) ctx[((size_t)bh*NBF + m)*DH + t] = wacc[0][t]+wacc[1][t]+wacc[2][t]+wacc[3][t];
}

// Performer Q side, fused: dd -> row stab -> qp -> Dinv -> og, one block per (b,h,i).
__global__ __launch_bounds__(128) void k_qattn(const float* __restrict__ q, const float* __restrict__ proj,
        const float* __restrict__ ctx, const float* __restrict__ ksum, float* __restrict__ o){
  int row = blockIdx.x;
  int bh = row >> 13, i = row & (NTOK-1);
  int b = bh >> 3, h = bh & 7;
  __shared__ float ql[DH];
  __shared__ float ctxl[NBF*DH];
  __shared__ float qp[NBF];
  __shared__ float red[128];
  int t = threadIdx.x;
  const float* qr = q + (size_t)(b*NTOK + i)*C + h*DH;
  if (t < DH) ql[t] = qr[t];
  for (int idx = t; idx < NBF*DH; idx += 128) ctxl[idx] = ctx[(size_t)bh*NBF*DH + idx];
  __syncthreads();
  float dd = -1e30f;
  if (t < NBF){
    const float* pm = proj + t*DH;
    float a = 0.f;
    #pragma unroll
    for (int d = 0; d < DH; d++) a += ql[d]*pm[d];
    dd = a * F_DN;
  }
  red[t] = dd;
  __syncthreads();
  #pragma unroll
  for (int o2 = 64; o2; o2 >>= 1){
    if (t < o2) red[t] = fmaxf(red[t], red[t+o2]);
    __syncthreads();
  }
  float stabv = red[0];
  __syncthreads();
  float sq = 0.f;
  #pragma unroll
  for (int d = 0; d < DH; d++) sq += ql[d]*ql[d];
  float diagv = 0.5f*F_DN*F_DN*sq;
  float qpv = 0.f;
  if (t < NBF){
    qpv = F_RNORM*(expf(dd - diagv - stabv) + 1e-4f);
    qp[t] = qpv;
  }
  red[t] = (t < NBF) ? qpv*ksum[bh*NBF + t] : 0.f;
  __syncthreads();
  #pragma unroll
  for (int o2 = 64; o2; o2 >>= 1){
    if (t < o2) red[t] += red[t+o2];
    __syncthreads();
  }
  float Dinv = 1.f/red[0];
  if (t < DH){
    float a = 0.f;
    for (int m = 0; m < NBF; m++) a += qp[m]*ctxl[m*DH + t];
    o[(size_t)(b*NTOK + i)*C + h*DH + t] = a*Dinv;
  }
}

// Local windowed attention, heads 8..15, one wave per (b, hl, window), online softmax.
__global__ __launch_bounds__(64) void k_local(const float* __restrict__ q, const float* __restrict__ k,
        const float* __restrict__ v, float* __restrict__ o){
  int blk = blockIdx.x;
  int w = blk & (NW-1);
  int rem = blk >> 7;
  int hl = rem & 7, b = rem >> 3;
  int hd = GH + hl;
  __shared__ float kl[3*WIN][DH];
  __shared__ float vl[3*WIN][DH];
  int t = threadIdx.x;
  int jstart = (w == 0) ? WIN : 0;
  int jend   = (w == NW-1) ? 2*WIN : 3*WIN;
  int nrows = jend - jstart;
  for (int idx = t; idx < nrows*DH; idx += 64){
    int j = jstart + (idx >> 5), d = idx & 31;
    int pos = (w-1)*WIN + j;
    size_t gidx = (size_t)(b*NTOK + pos)*C + hd*DH + d;
    kl[j][d] = k[gidx];
    vl[j][d] = v[gidx];
  }
  __syncthreads();
  size_t qg = (size_t)(b*NTOK + w*WIN + t)*C + hd*DH;
  float qreg[DH];
  #pragma unroll
  for (int d = 0; d < DH; d++) qreg[d] = q[qg + d]*F_LSCALE;
  float mx = -1e30f, l = 0.f;
  float acc[DH] = {};
  for (int j = jstart; j < jend; j++){
    float s = 0.f;
    #pragma unroll
    for (int d = 0; d < DH; d++) s += qreg[d]*kl[j][d];
    float nm = fmaxf(mx, s);
    float corr = expf(mx - nm);
    float pexp = expf(s - nm);
    l = l*corr + pexp;
    #pragma unroll
    for (int d = 0; d < DH; d++) acc[d] = acc[d]*corr + pexp*vl[j][d];
    mx = nm;
  }
  float inv = 1.f/l;
  #pragma unroll
  for (int d = 0; d < DH; d++) o[qg + d] = acc[d]*inv;
}

} // namespace

extern "C" void kernel_launch(void* const* d_in, const int* in_sizes, int n_in,
                              void* d_out, int out_size, void* d_ws, size_t ws_size,
                              hipStream_t stream){
  (void)in_sizes; (void)n_in; (void)out_size; (void)ws_size;
  const float* x     = (const float*)d_in[0];
  const float* ln1_g = (const float*)d_in[1];
  const float* ln1_b = (const float*)d_in[2];
  const float* Wq    = (const float*)d_in[3];
  const float* bq    = (const float*)d_in[4];
  const float* Wk    = (const float*)d_in[5];
  const float* bk    = (const float*)d_in[6];
  const float* Wv    = (const float*)d_in[7];
  const float* bv    = (const float*)d_in[8];
  const float* Wo    = (const float*)d_in[9];
  const float* bo    = (const float*)d_in[10];
  const float* proj  = (const float*)d_in[11];
  const float* ln2_g = (const float*)d_in[12];
  const float* ln2_b = (const float*)d_in[13];
  const float* W1    = (const float*)d_in[14];
  const float* b1    = (const float*)d_in[15];
  const float* W2    = (const float*)d_in[16];
  const float* b2    = (const float*)d_in[17];

  float* h  = (float*)d_out;
  float* ws = (float*)d_ws;
  const size_t MC = (size_t)MROWS*C;
  size_t off = 0;
  float* y    = ws + off;  off += MC;                 // reused as attention output 'o'
  float* qb_  = ws + off;  off += MC;
  float* kb_  = ws + off;  off += MC;
  float* vb_  = ws + off;  off += MC;
  float* diag = ws + off;  off += (size_t)16*NTOK;
  float* cost = ws + off;  off += (size_t)NTOK*16;
  float* sint = ws + off;  off += (size_t)NTOK*16;
  float* ctxb = ws + off;  off += (size_t)16*NBF*DH;
  float* ksum = ws + off;  off += (size_t)16*NBF;
  unsigned* stab = (unsigned*)(ws + off);
  float* mid = qb_;   // FFN intermediate (M*FF) aliases q+k (dead by then)
  float* o   = y;

  k_tables<<<(NTOK*16 + 255)/256, 256, 0, stream>>>(cost, sint);
  k_copy<<<(int)((MC/4 + 255)/256), 256, 0, stream>>>((const float4*)x, (float4*)h, (int)(MC/4));

  dim3 blk(256);
  dim3 g512(C/128, MROWS/128);
  dim3 gff(FF/128, MROWS/128);

  for (int l = 0; l < 2; l++){
    const float* pj = proj + (size_t)l*NBF*DH;
    k_ln<<<MROWS, 256, 0, stream>>>(h, ln1_g + l*C, ln1_b + l*C, y);
    k_gemm<0><<<g512, blk, 0, stream>>>(y, Wq + (size_t)l*C*C, bq + l*C, nullptr, qb_, MROWS, C, C);
    k_gemm<0><<<g512, blk, 0, stream>>>(y, Wk + (size_t)l*C*C, bk + l*C, nullptr, kb_, MROWS, C, C);
    k_gemm<0><<<g512, blk, 0, stream>>>(y, Wv + (size_t)l*C*C, bv + l*C, nullptr, vb_, MROWS, C, C);
    k_rope<<<(MROWS*128)/256, 256, 0, stream>>>(qb_, kb_, cost, sint);
    k_zstab<<<1, 16, 0, stream>>>(stab);
    k_kstab<<<16*NTOK, 128, 0, stream>>>(kb_, pj, diag, stab);
    k_ctx<<<16*NBF, 256, 0, stream>>>(kb_, vb_, pj, diag, stab, ctxb, ksum);
    k_qattn<<<16*NTOK, 128, 0, stream>>>(qb_, pj, ctxb, ksum, o);
    k_local<<<BATCH*8*NW, 64, 0, stream>>>(qb_, kb_, vb_, o);
    k_gemm<0><<<g512, blk, 0, stream>>>(o, Wo + (size_t)l*C*C, bo + l*C, h, h, MROWS, C, C);
    k_ln<<<MROWS, 256, 0, stream>>>(h, ln2_g + l*C, ln2_b + l*C, y);
    k_gemm<1><<<gff, blk, 0, stream>>>(y, W1 + (size_t)l*C*FF, b1 + l*FF, nullptr, mid, MROWS, FF, C);
    k_gemm<0><<<g512, blk, 0, stream>>>(mid, W2 + (size_t)l*FF*C, b2 + l*C, h, h, MROWS, C, FF);
  }
}

// Round 2
// 1786.079 us; speedup vs baseline: 4.0630x; 4.0630x over previous
//
#include <hip/hip_runtime.h>
#include <math.h>

namespace {

constexpr int BATCH = 2;
constexpr int NTOK  = 8192;    // tokens per batch (T*H*W)
constexpr int MROWS = 16384;   // BATCH*NTOK
constexpr int C     = 512;
constexpr int GH    = 8;
constexpr int DH    = 32;
constexpr int WIN   = 64;
constexpr int NW    = 128;     // NTOK/WIN
constexpr int FF    = 1024;
constexpr int NBF   = 110;     // int(32*ln(32))

constexpr float F_DN     = 0.42044820762685725f;   // 32^-0.25
constexpr float F_RNORM  = 0.09534625892455924f;   // 110^-0.5
constexpr float F_LSCALE = 0.17677669529663687f;   // 32^-0.5

typedef __attribute__((ext_vector_type(8))) short bf16x8;
typedef __attribute__((ext_vector_type(4))) float f32x4;

__device__ __forceinline__ ushort f2b(float f){
  unsigned u = __float_as_uint(f);
  unsigned r = u + 0x7FFFu + ((u >> 16) & 1u);
  return (ushort)(r >> 16);
}

__device__ __forceinline__ void gload16(const void* g, void* l){
  __builtin_amdgcn_global_load_lds((const __attribute__((address_space(1))) void*)g,
                                   (__attribute__((address_space(3))) void*)l, 16, 0, 0);
}

__global__ void k_tables(float* __restrict__ cost, float* __restrict__ sint){
  int idx = blockIdx.x*256 + threadIdx.x;
  if (idx >= NTOK*16) return;
  int pos = idx >> 4, f = idx & 15;
  float inv = powf(10000.f, -(float)f/16.f);
  float ang = (float)pos * inv;
  cost[idx] = cosf(ang);
  sint[idx] = sinf(ang);
}

__global__ void k_copy(const float4* __restrict__ s, float4* __restrict__ d, int n){
  int i = blockIdx.x*256 + threadIdx.x;
  if (i < n) d[i] = s[i];
}

// fp32 (K,N) -> bf16 transposed (N,K)
__global__ __launch_bounds__(256) void k_wcvt(const float* __restrict__ W, ushort* __restrict__ Wt,
                                              int K, int N){
  __shared__ float t[32][33];
  int bx = blockIdx.x, by = blockIdx.y;
  int tx = threadIdx.x & 31, ty = threadIdx.x >> 5;
  #pragma unroll
  for (int r = ty; r < 32; r += 8) t[r][tx] = W[(size_t)(by*32+r)*N + bx*32 + tx];
  __syncthreads();
  #pragma unroll
  for (int r = ty; r < 32; r += 8) Wt[(size_t)(bx*32+r)*K + by*32 + tx] = f2b(t[tx][r]);
}

__global__ __launch_bounds__(256) void k_ln(const float* __restrict__ x, const float* __restrict__ g,
                     const float* __restrict__ b, ushort* __restrict__ y){
  int row = blockIdx.x, t = threadIdx.x;
  const float* xr = x + (size_t)row*C;
  float2 v = *(const float2*)(xr + 2*t);
  float s = v.x + v.y, ss = v.x*v.x + v.y*v.y;
  #pragma unroll
  for (int o = 32; o; o >>= 1){ s += __shfl_down(s, o); ss += __shfl_down(ss, o); }
  __shared__ float rs[4], rss[4];
  int wv = t >> 6, ln = t & 63;
  if (ln == 0){ rs[wv] = s; rss[wv] = ss; }
  __syncthreads();
  float S = rs[0]+rs[1]+rs[2]+rs[3], SS = rss[0]+rss[1]+rss[2]+rss[3];
  float mean = S * (1.f/C);
  float var  = SS * (1.f/C) - mean*mean;
  float rstd = rsqrtf(var + 1e-5f);
  float2 gg = *(const float2*)(g + 2*t);
  float2 bb = *(const float2*)(b + 2*t);
  ushort2 ov;
  ov.x = f2b((v.x - mean)*rstd*gg.x + bb.x);
  ov.y = f2b((v.y - mean)*rstd*gg.y + bb.y);
  *(ushort2*)(y + (size_t)row*C + 2*t) = ov;
}

// bf16 MFMA GEMM, m97 structure: out = ACT(A@B + bias) (+res)
// A: (M,K) bf16 row-major.  Bt: (N,K) bf16 row-major (i.e. B^T).
// grid (Nd/128, M/128), 256 threads (4 waves, 2x2 of 64x64).
template<int ACT, int OBF>
__global__ __launch_bounds__(256) void k_mgemm(const ushort* __restrict__ A, const ushort* __restrict__ Bt,
      const float* __restrict__ bias, const float* __restrict__ res,
      float* __restrict__ outf, ushort* __restrict__ outb, int Nd, int Kd){
  __shared__ ushort As[128*32];
  __shared__ ushort Bs[128*32];
  int tid = threadIdx.x;
  int lane = tid & 63, wave = tid >> 6;
  int wr = wave >> 1, wc = wave & 1;
  int row0 = blockIdx.y*128, col0 = blockIdx.x*128;
  f32x4 acc[4][4] = {};
  for (int k0 = 0; k0 < Kd; k0 += 32){
    __syncthreads();
    #pragma unroll
    for (int c = 0; c < 2; c++){
      int off = (wave*2 + c)*1024 + lane*16;       // byte offset in 8KB tile
      int r = off >> 6, ke = (off & 63) >> 1;      // row, k-element
      gload16(A  + (size_t)(row0 + r)*Kd + k0 + ke, (char*)As + (wave*2 + c)*1024);
      gload16(Bt + (size_t)(col0 + r)*Kd + k0 + ke, (char*)Bs + (wave*2 + c)*1024);
    }
    __syncthreads();
    bf16x8 af[4], bfr[4];
    #pragma unroll
    for (int m = 0; m < 4; m++)
      af[m] = *(const bf16x8*)((const char*)As + (wr*64 + m*16 + (lane&15))*64 + (lane>>4)*16);
    #pragma unroll
    for (int n = 0; n < 4; n++)
      bfr[n] = *(const bf16x8*)((const char*)Bs + (wc*64 + n*16 + (lane&15))*64 + (lane>>4)*16);
    #pragma unroll
    for (int m = 0; m < 4; m++)
      #pragma unroll
      for (int n = 0; n < 4; n++)
        acc[m][n] = __builtin_amdgcn_mfma_f32_16x16x32_bf16(af[m], bfr[n], acc[m][n], 0, 0, 0);
  }
  #pragma unroll
  for (int m = 0; m < 4; m++){
    int rbase = row0 + wr*64 + m*16 + (lane>>4)*4;
    #pragma unroll
    for (int n = 0; n < 4; n++){
      int ccol = col0 + wc*64 + n*16 + (lane&15);
      float bv = bias[ccol];
      #pragma unroll
      for (int r = 0; r < 4; r++){
        int grow = rbase + r;
        float vv = acc[m][n][r] + bv;
        if (ACT == 1) vv = 0.5f*vv*(1.f + erff(vv*0.7071067811865476f));
        if (res) vv += res[(size_t)grow*Nd + ccol];
        if (OBF) outb[(size_t)grow*Nd + ccol] = f2b(vv);
        else     outf[(size_t)grow*Nd + ccol] = vv;
      }
    }
  }
}

// RoPE in place on local-head channels [256,512) of q and k.
__global__ void k_rope(float* __restrict__ q, float* __restrict__ k,
                       const float* __restrict__ cost, const float* __restrict__ sint){
  int idx = blockIdx.x*256 + threadIdx.x;
  if (idx >= MROWS*128) return;
  int r = idx >> 7, p = idx & 127;
  int head = p >> 4, d = p & 15;
  int pos = r & (NTOK-1);
  float cv = cost[pos*16+d], sv = sint[pos*16+d];
  size_t base = (size_t)r*C + 256 + head*32 + d;
  float a = q[base], b2 = q[base+16];
  q[base]    = a*cv - b2*sv;
  q[base+16] = b2*cv + a*sv;
  float ka = k[base], kb = k[base+16];
  k[base]    = ka*cv - kb*sv;
  k[base+16] = kb*cv + ka*sv;
}

// Performer K pre-pass: per-row diag + per-(bh,chunk) max of dd. No atomics.
__global__ __launch_bounds__(256) void k_kpre(const float* __restrict__ k, const float* __restrict__ proj,
        float* __restrict__ diag, float* __restrict__ bmax){
  int bh = blockIdx.x >> 5, chunk = blockIdx.x & 31;
  int b = bh >> 3, h = bh & 7;
  __shared__ float pl[NBF][DH];
  int t = threadIdx.x;
  for (int idx = t; idx < NBF*DH; idx += 256) pl[idx>>5][idx&31] = proj[idx]*F_DN;
  __syncthreads();
  int i = chunk*256 + t;
  const float* kr = k + (size_t)(b*NTOK + i)*C + h*DH;
  float kv[DH];
  #pragma unroll
  for (int f = 0; f < 8; f++) *(float4*)&kv[f*4] = *(const float4*)(kr + f*4);
  float sq = 0.f;
  #pragma unroll
  for (int d = 0; d < DH; d++) sq += kv[d]*kv[d];
  diag[bh*NTOK + i] = 0.5f*F_DN*F_DN*sq;
  float mx = -1e30f;
  for (int m = 0; m < NBF; m++){
    float a = 0.f;
    #pragma unroll
    for (int d = 0; d < DH; d++) a += kv[d]*pl[m][d];
    mx = fmaxf(mx, a);
  }
  #pragma unroll
  for (int o = 32; o; o >>= 1) mx = fmaxf(mx, __shfl_down(mx, o));
  __shared__ float red[4];
  if ((t & 63) == 0) red[t>>6] = mx;
  __syncthreads();
  if (t == 0) bmax[bh*32 + chunk] = fmaxf(fmaxf(red[0],red[1]), fmaxf(red[2],red[3]));
}

__global__ void k_redmax(const float* __restrict__ bmax, float* __restrict__ stabf){
  int bh = blockIdx.x, t = threadIdx.x;
  float v = (t < 32) ? bmax[bh*32 + t] : -1e30f;
  #pragma unroll
  for (int o = 32; o; o >>= 1) v = fmaxf(v, __shfl_down(v, o));
  if (t == 0) stabf[bh] = v;
}

// Performer K pass 2: K/V staged once per chunk in LDS; thread t owns feature m=t.
__global__ __launch_bounds__(128) void k_ctx2(const float* __restrict__ k, const float* __restrict__ v,
        const float* __restrict__ proj, const float* __restrict__ diag, const float* __restrict__ stabf,
        float* __restrict__ ctxp, float* __restrict__ ksump){
  int bh = blockIdx.x >> 6, chunk = blockIdx.x & 63;
  int b = bh >> 3, h = bh & 7;
  __shared__ float pl[NBF][33];
  __shared__ float kl[128][DH];
  __shared__ float vl[128][DH];
  __shared__ float dg[128];
  int t = threadIdx.x;
  for (int idx = t; idx < NBF*DH; idx += 128){ int m = idx>>5, d = idx&31; pl[m][d] = proj[idx]*F_DN; }
  int i0 = chunk*128;
  for (int idx = t; idx < 128*8; idx += 128){
    int r = idx >> 3, f = idx & 7;
    size_t gofs = (size_t)(b*NTOK + i0 + r)*C + h*DH + f*4;
    *(float4*)&kl[r][f*4] = *(const float4*)(k + gofs);
    *(float4*)&vl[r][f*4] = *(const float4*)(v + gofs);
  }
  dg[t] = diag[bh*NTOK + i0 + t];
  __syncthreads();
  float st = stabf[bh];
  if (t < NBF){
    float acc[DH] = {};
    float ks = 0.f;
    for (int r = 0; r < 128; r++){
      float dd = 0.f;
      #pragma unroll
      for (int d = 0; d < DH; d++) dd += kl[r][d]*pl[t][d];
      float kp = F_RNORM*(expf(dd - dg[r] - st) + 1e-4f);
      ks += kp;
      #pragma unroll
      for (int d = 0; d < DH; d++) acc[d] += kp*vl[r][d];
    }
    size_t base = (((size_t)bh*64 + chunk)*NBF + t)*DH;
    #pragma unroll
    for (int d = 0; d < DH; d++) ctxp[base + d] = acc[d];
    ksump[((size_t)bh*64 + chunk)*NBF + t] = ks;
  }
}

__global__ void k_ctxred(const float* __restrict__ ctxp, const float* __restrict__ ksump,
                         float* __restrict__ ctx, float* __restrict__ ksum){
  int bh = blockIdx.x / NBF, m = blockIdx.x % NBF;
  int t = threadIdx.x;
  if (t < DH){
    float s = 0.f;
    for (int c = 0; c < 64; c++) s += ctxp[(((size_t)bh*64 + c)*NBF + m)*DH + t];
    ctx[((size_t)bh*NBF + m)*DH + t] = s;
  } else if (t == DH){
    float s = 0.f;
    for (int c = 0; c < 64; c++) s += ksump[((size_t)bh*64 + c)*NBF + m];
    ksum[bh*NBF + m] = s;
  }
}

// Performer Q side, fused: dd -> row stab -> qp -> Dinv -> og, one block per (b,h,i).
__global__ __launch_bounds__(128) void k_qattn(const float* __restrict__ q, const float* __restrict__ proj,
        const float* __restrict__ ctx, const float* __restrict__ ksum, ushort* __restrict__ o){
  int row = blockIdx.x;
  int bh = row >> 13, i = row & (NTOK-1);
  int b = bh >> 3, h = bh & 7;
  __shared__ float ql[DH];
  __shared__ float ctxl[NBF*DH];
  __shared__ float qp[NBF];
  __shared__ float red[128];
  int t = threadIdx.x;
  const float* qr = q + (size_t)(b*NTOK + i)*C + h*DH;
  if (t < DH) ql[t] = qr[t];
  for (int idx = t; idx < NBF*DH; idx += 128) ctxl[idx] = ctx[(size_t)bh*NBF*DH + idx];
  __syncthreads();
  float dd = -1e30f;
  if (t < NBF){
    const float* pm = proj + t*DH;
    float a = 0.f;
    #pragma unroll
    for (int d = 0; d < DH; d++) a += ql[d]*pm[d];
    dd = a * F_DN;
  }
  red[t] = dd;
  __syncthreads();
  #pragma unroll
  for (int o2 = 64; o2; o2 >>= 1){
    if (t < o2) red[t] = fmaxf(red[t], red[t+o2]);
    __syncthreads();
  }
  float stabv = red[0];
  __syncthreads();
  float sq = 0.f;
  #pragma unroll
  for (int d = 0; d < DH; d++) sq += ql[d]*ql[d];
  float diagv = 0.5f*F_DN*F_DN*sq;
  float qpv = 0.f;
  if (t < NBF){
    qpv = F_RNORM*(expf(dd - diagv - stabv) + 1e-4f);
    qp[t] = qpv;
  }
  red[t] = (t < NBF) ? qpv*ksum[bh*NBF + t] : 0.f;
  __syncthreads();
  #pragma unroll
  for (int o2 = 64; o2; o2 >>= 1){
    if (t < o2) red[t] += red[t+o2];
    __syncthreads();
  }
  float Dinv = 1.f/red[0];
  if (t < DH){
    float a = 0.f;
    for (int m = 0; m < NBF; m++) a += qp[m]*ctxl[m*DH + t];
    o[(size_t)(b*NTOK + i)*C + h*DH + t] = f2b(a*Dinv);
  }
}

// Local windowed attention, heads 8..15, one wave per (b, hl, window), online softmax.
__global__ __launch_bounds__(64) void k_local(const float* __restrict__ q, const float* __restrict__ k,
        const float* __restrict__ v, ushort* __restrict__ o){
  int blk = blockIdx.x;
  int w = blk & (NW-1);
  int rem = blk >> 7;
  int hl = rem & 7, b = rem >> 3;
  int hd = GH + hl;
  __shared__ float kl[3*WIN][DH];
  __shared__ float vl[3*WIN][DH];
  int t = threadIdx.x;
  int jstart = (w == 0) ? WIN : 0;
  int jend   = (w == NW-1) ? 2*WIN : 3*WIN;
  int nrows = jend - jstart;
  for (int idx = t; idx < nrows*DH; idx += 64){
    int j = jstart + (idx >> 5), d = idx & 31;
    int pos = (w-1)*WIN + j;
    size_t gidx = (size_t)(b*NTOK + pos)*C + hd*DH + d;
    kl[j][d] = k[gidx];
    vl[j][d] = v[gidx];
  }
  __syncthreads();
  size_t qg = (size_t)(b*NTOK + w*WIN + t)*C + hd*DH;
  float qreg[DH];
  #pragma unroll
  for (int d = 0; d < DH; d++) qreg[d] = q[qg + d]*F_LSCALE;
  float mx = -1e30f, l = 0.f;
  float acc[DH] = {};
  for (int j = jstart; j < jend; j++){
    float s = 0.f;
    #pragma unroll
    for (int d = 0; d < DH; d++) s += qreg[d]*kl[j][d];
    float nm = fmaxf(mx, s);
    float corr = expf(mx - nm);
    float pexp = expf(s - nm);
    l = l*corr + pexp;
    #pragma unroll
    for (int d = 0; d < DH; d++) acc[d] = acc[d]*corr + pexp*vl[j][d];
    mx = nm;
  }
  float inv = 1.f/l;
  #pragma unroll
  for (int d = 0; d < DH; d++) o[qg + d] = f2b(acc[d]*inv);
}

} // namespace

extern "C" void kernel_launch(void* const* d_in, const int* in_sizes, int n_in,
                              void* d_out, int out_size, void* d_ws, size_t ws_size,
                              hipStream_t stream){
  (void)in_sizes; (void)n_in; (void)out_size; (void)ws_size;
  const float* x     = (const float*)d_in[0];
  const float* ln1_g = (const float*)d_in[1];
  const float* ln1_b = (const float*)d_in[2];
  const float* Wq    = (const float*)d_in[3];
  const float* bq    = (const float*)d_in[4];
  const float* Wk    = (const float*)d_in[5];
  const float* bk    = (const float*)d_in[6];
  const float* Wv    = (const float*)d_in[7];
  const float* bv    = (const float*)d_in[8];
  const float* Wo    = (const float*)d_in[9];
  const float* bo    = (const float*)d_in[10];
  const float* proj  = (const float*)d_in[11];
  const float* ln2_g = (const float*)d_in[12];
  const float* ln2_b = (const float*)d_in[13];
  const float* W1    = (const float*)d_in[14];
  const float* b1    = (const float*)d_in[15];
  const float* W2    = (const float*)d_in[16];
  const float* b2    = (const float*)d_in[17];

  float* h = (float*)d_out;
  const size_t MC = (size_t)MROWS*C;
  char* w = (char*)d_ws;
  auto alloc = [&](size_t bytes)->char*{ char* p = w; w += (bytes + 255) & ~(size_t)255; return p; };

  ushort* y16  = (ushort*)alloc(MC*2);
  float*  qb   = (float*) alloc(MC*4);
  float*  kb   = (float*) alloc(MC*4);
  float*  vb   = (float*) alloc(MC*4);
  ushort* o16  = (ushort*)alloc(MC*2);
  ushort* wt   = (ushort*)alloc((size_t)2097152*2);   // per-layer transposed bf16 weights
  float*  cost = (float*) alloc((size_t)NTOK*16*4);
  float*  sint = (float*) alloc((size_t)NTOK*16*4);
  float*  diag = (float*) alloc((size_t)16*NTOK*4);
  float*  bmax = (float*) alloc(16*32*4);
  float*  stabf= (float*) alloc(16*4);
  float*  ctxb = (float*) alloc((size_t)16*NBF*DH*4);
  float*  ksum = (float*) alloc((size_t)16*NBF*4);

  ushort* mid16 = (ushort*)qb;             // FFN intermediate (M*FF bf16 = 33.6MB) aliases q (dead)
  float*  ctxp  = (float*)o16;             // ctx partials (14.4MB) alias o16 (written later)
  float*  ksump = ctxp + (size_t)16*64*NBF*DH;

  ushort* wtq = wt;
  ushort* wtk = wt +  262144;
  ushort* wtv = wt +  524288;
  ushort* wto = wt +  786432;
  ushort* wt1 = wt + 1048576;
  ushort* wt2 = wt + 1572864;

  k_tables<<<(NTOK*16 + 255)/256, 256, 0, stream>>>(cost, sint);
  k_copy<<<(int)((MC/4 + 255)/256), 256, 0, stream>>>((const float4*)x, (float4*)h, (int)(MC/4));

  dim3 blk(256);
  dim3 g512(4, 128);    // N=512
  dim3 gff(8, 128);     // N=1024

  for (int l = 0; l < 2; l++){
    const float* pj = proj + (size_t)l*NBF*DH;
    k_wcvt<<<dim3(16,16), blk, 0, stream>>>(Wq + (size_t)l*C*C,  wtq, C, C);
    k_wcvt<<<dim3(16,16), blk, 0, stream>>>(Wk + (size_t)l*C*C,  wtk, C, C);
    k_wcvt<<<dim3(16,16), blk, 0, stream>>>(Wv + (size_t)l*C*C,  wtv, C, C);
    k_wcvt<<<dim3(16,16), blk, 0, stream>>>(Wo + (size_t)l*C*C,  wto, C, C);
    k_wcvt<<<dim3(32,16), blk, 0, stream>>>(W1 + (size_t)l*C*FF, wt1, C, FF);
    k_wcvt<<<dim3(16,32), blk, 0, stream>>>(W2 + (size_t)l*FF*C, wt2, FF, C);

    k_ln<<<MROWS, 256, 0, stream>>>(h, ln1_g + l*C, ln1_b + l*C, y16);
    k_mgemm<0,0><<<g512, blk, 0, stream>>>(y16, wtq, bq + l*C, nullptr, qb, nullptr, C, C);
    k_mgemm<0,0><<<g512, blk, 0, stream>>>(y16, wtk, bk + l*C, nullptr, kb, nullptr, C, C);
    k_mgemm<0,0><<<g512, blk, 0, stream>>>(y16, wtv, bv + l*C, nullptr, vb, nullptr, C, C);
    k_rope<<<(MROWS*128)/256, 256, 0, stream>>>(qb, kb, cost, sint);
    k_kpre<<<16*32, 256, 0, stream>>>(kb, pj, diag, bmax);
    k_redmax<<<16, 64, 0, stream>>>(bmax, stabf);
    k_ctx2<<<16*64, 128, 0, stream>>>(kb, vb, pj, diag, stabf, ctxp, ksump);
    k_ctxred<<<16*NBF, 64, 0, stream>>>(ctxp, ksump, ctxb, ksum);
    k_qattn<<<16*NTOK, 128, 0, stream>>>(qb, pj, ctxb, ksum, o16);
    k_local<<<BATCH*8*NW, 64, 0, stream>>>(qb, kb, vb, o16);
    k_mgemm<0,0><<<g512, blk, 0, stream>>>(o16, wto, bo + l*C, h, h, nullptr, C, C);
    k_ln<<<MROWS, 256, 0, stream>>>(h, ln2_g + l*C, ln2_b + l*C, y16);
    k_mgemm<1,1><<<gff, blk, 0, stream>>>(y16, wt1, b1 + l*FF, nullptr, nullptr, mid16, FF, C);
    k_mgemm<0,0><<<g512, blk, 0, stream>>>(mid16, wt2, b2 + l*C, h, h, nullptr, C, FF);
  }
}

// Round 3
// 1363.479 us; speedup vs baseline: 5.3223x; 1.3099x over previous
//
#include <hip/hip_runtime.h>
#include <math.h>

namespace {

constexpr int BATCH = 2;
constexpr int NTOK  = 8192;    // tokens per batch (T*H*W)
constexpr int MROWS = 16384;   // BATCH*NTOK
constexpr int C     = 512;
constexpr int GH    = 8;
constexpr int DH    = 32;
constexpr int WIN   = 64;
constexpr int NW    = 128;     // NTOK/WIN
constexpr int FF    = 1024;
constexpr int NBF   = 110;     // int(32*ln(32))

constexpr float F_DN     = 0.42044820762685725f;   // 32^-0.25
constexpr float F_RNORM  = 0.09534625892455924f;   // 110^-0.5
constexpr float F_LSCALE = 0.17677669529663687f;   // 32^-0.5

typedef __attribute__((ext_vector_type(8))) short bf16x8;
typedef __attribute__((ext_vector_type(4))) float f32x4;

__device__ __forceinline__ ushort f2b(float f){
  unsigned u = __float_as_uint(f);
  unsigned r = u + 0x7FFFu + ((u >> 16) & 1u);
  return (ushort)(r >> 16);
}

__device__ __forceinline__ void gload16(const void* g, void* l){
  __builtin_amdgcn_global_load_lds((const __attribute__((address_space(1))) void*)g,
                                   (__attribute__((address_space(3))) void*)l, 16, 0, 0);
}

__global__ void k_tables(float* __restrict__ cost, float* __restrict__ sint){
  int idx = blockIdx.x*256 + threadIdx.x;
  if (idx >= NTOK*16) return;
  int pos = idx >> 4, f = idx & 15;
  float inv = powf(10000.f, -(float)f/16.f);
  float ang = (float)pos * inv;
  cost[idx] = cosf(ang);
  sint[idx] = sinf(ang);
}

__global__ void k_copy(const float4* __restrict__ s, float4* __restrict__ d, int n){
  int i = blockIdx.x*256 + threadIdx.x;
  if (i < n) d[i] = s[i];
}

// fp32 (K,N) -> bf16 transposed (N,K)
__global__ __launch_bounds__(256) void k_wcvt(const float* __restrict__ W, ushort* __restrict__ Wt,
                                              int K, int N){
  __shared__ float t[32][33];
  int bx = blockIdx.x, by = blockIdx.y;
  int tx = threadIdx.x & 31, ty = threadIdx.x >> 5;
  #pragma unroll
  for (int r = ty; r < 32; r += 8) t[r][tx] = W[(size_t)(by*32+r)*N + bx*32 + tx];
  __syncthreads();
  #pragma unroll
  for (int r = ty; r < 32; r += 8) Wt[(size_t)(bx*32+r)*K + by*32 + tx] = f2b(t[tx][r]);
}

__global__ __launch_bounds__(256) void k_ln(const float* __restrict__ x, const float* __restrict__ g,
                     const float* __restrict__ b, ushort* __restrict__ y){
  int row = blockIdx.x, t = threadIdx.x;
  const float* xr = x + (size_t)row*C;
  float2 v = *(const float2*)(xr + 2*t);
  float s = v.x + v.y, ss = v.x*v.x + v.y*v.y;
  #pragma unroll
  for (int o = 32; o; o >>= 1){ s += __shfl_down(s, o); ss += __shfl_down(ss, o); }
  __shared__ float rs[4], rss[4];
  int wv = t >> 6, ln = t & 63;
  if (ln == 0){ rs[wv] = s; rss[wv] = ss; }
  __syncthreads();
  float S = rs[0]+rs[1]+rs[2]+rs[3], SS = rss[0]+rss[1]+rss[2]+rss[3];
  float mean = S * (1.f/C);
  float var  = SS * (1.f/C) - mean*mean;
  float rstd = rsqrtf(var + 1e-5f);
  float2 gg = *(const float2*)(g + 2*t);
  float2 bb = *(const float2*)(b + 2*t);
  ushort2 ov;
  ov.x = f2b((v.x - mean)*rstd*gg.x + bb.x);
  ov.y = f2b((v.y - mean)*rstd*gg.y + bb.y);
  *(ushort2*)(y + (size_t)row*C + 2*t) = ov;
}

// bf16 MFMA GEMM, m97 structure: out = ACT(A@B + bias) (+res)
// A: (M,K) bf16 row-major.  Bt: (N,K) bf16 row-major (i.e. B^T).
// grid (Nd/128, M/128), 256 threads (4 waves, 2x2 of 64x64).
template<int ACT, int OBF>
__global__ __launch_bounds__(256) void k_mgemm(const ushort* __restrict__ A, const ushort* __restrict__ Bt,
      const float* __restrict__ bias, const float* __restrict__ res,
      float* __restrict__ outf, ushort* __restrict__ outb, int Nd, int Kd){
  __shared__ ushort As[128*32];
  __shared__ ushort Bs[128*32];
  int tid = threadIdx.x;
  int lane = tid & 63, wave = tid >> 6;
  int wr = wave >> 1, wc = wave & 1;
  int row0 = blockIdx.y*128, col0 = blockIdx.x*128;
  f32x4 acc[4][4] = {};
  for (int k0 = 0; k0 < Kd; k0 += 32){
    __syncthreads();
    #pragma unroll
    for (int c = 0; c < 2; c++){
      int off = (wave*2 + c)*1024 + lane*16;       // byte offset in 8KB tile
      int r = off >> 6, ke = (off & 63) >> 1;      // row, k-element
      gload16(A  + (size_t)(row0 + r)*Kd + k0 + ke, (char*)As + (wave*2 + c)*1024);
      gload16(Bt + (size_t)(col0 + r)*Kd + k0 + ke, (char*)Bs + (wave*2 + c)*1024);
    }
    __syncthreads();
    bf16x8 af[4], bfr[4];
    #pragma unroll
    for (int m = 0; m < 4; m++)
      af[m] = *(const bf16x8*)((const char*)As + (wr*64 + m*16 + (lane&15))*64 + (lane>>4)*16);
    #pragma unroll
    for (int n = 0; n < 4; n++)
      bfr[n] = *(const bf16x8*)((const char*)Bs + (wc*64 + n*16 + (lane&15))*64 + (lane>>4)*16);
    #pragma unroll
    for (int m = 0; m < 4; m++)
      #pragma unroll
      for (int n = 0; n < 4; n++)
        acc[m][n] = __builtin_amdgcn_mfma_f32_16x16x32_bf16(af[m], bfr[n], acc[m][n], 0, 0, 0);
  }
  #pragma unroll
  for (int m = 0; m < 4; m++){
    int rbase = row0 + wr*64 + m*16 + (lane>>4)*4;
    #pragma unroll
    for (int n = 0; n < 4; n++){
      int ccol = col0 + wc*64 + n*16 + (lane&15);
      float bv = bias[ccol];
      #pragma unroll
      for (int r = 0; r < 4; r++){
        int grow = rbase + r;
        float vv = acc[m][n][r] + bv;
        if (ACT == 1) vv = 0.5f*vv*(1.f + erff(vv*0.7071067811865476f));
        if (res) vv += res[(size_t)grow*Nd + ccol];
        if (OBF) outb[(size_t)grow*Nd + ccol] = f2b(vv);
        else     outf[(size_t)grow*Nd + ccol] = vv;
      }
    }
  }
}

// RoPE in place on local-head channels [256,512) of q and k.
__global__ void k_rope(float* __restrict__ q, float* __restrict__ k,
                       const float* __restrict__ cost, const float* __restrict__ sint){
  int idx = blockIdx.x*256 + threadIdx.x;
  if (idx >= MROWS*128) return;
  int r = idx >> 7, p = idx & 127;
  int head = p >> 4, d = p & 15;
  int pos = r & (NTOK-1);
  float cv = cost[pos*16+d], sv = sint[pos*16+d];
  size_t base = (size_t)r*C + 256 + head*32 + d;
  float a = q[base], b2 = q[base+16];
  q[base]    = a*cv - b2*sv;
  q[base+16] = b2*cv + a*sv;
  float ka = k[base], kb = k[base+16];
  k[base]    = ka*cv - kb*sv;
  k[base+16] = kb*cv + ka*sv;
}

// Performer K pre-pass: per-row diag + per-(bh,chunk) max of dd. No atomics.
__global__ __launch_bounds__(256) void k_kpre(const float* __restrict__ k, const float* __restrict__ proj,
        float* __restrict__ diag, float* __restrict__ bmax){
  int bh = blockIdx.x >> 5, chunk = blockIdx.x & 31;
  int b = bh >> 3, h = bh & 7;
  __shared__ float pl[NBF][DH];
  int t = threadIdx.x;
  for (int idx = t; idx < NBF*DH; idx += 256) pl[idx>>5][idx&31] = proj[idx]*F_DN;
  __syncthreads();
  int i = chunk*256 + t;
  const float* kr = k + (size_t)(b*NTOK + i)*C + h*DH;
  float kv[DH];
  #pragma unroll
  for (int f = 0; f < 8; f++) *(float4*)&kv[f*4] = *(const float4*)(kr + f*4);
  float sq = 0.f;
  #pragma unroll
  for (int d = 0; d < DH; d++) sq += kv[d]*kv[d];
  diag[bh*NTOK + i] = 0.5f*F_DN*F_DN*sq;
  float mx = -1e30f;
  for (int m = 0; m < NBF; m++){
    float a = 0.f;
    #pragma unroll
    for (int d = 0; d < DH; d++) a += kv[d]*pl[m][d];
    mx = fmaxf(mx, a);
  }
  #pragma unroll
  for (int o = 32; o; o >>= 1) mx = fmaxf(mx, __shfl_down(mx, o));
  __shared__ float red[4];
  if ((t & 63) == 0) red[t>>6] = mx;
  __syncthreads();
  if (t == 0) bmax[bh*32 + chunk] = fmaxf(fmaxf(red[0],red[1]), fmaxf(red[2],red[3]));
}

__global__ void k_redmax(const float* __restrict__ bmax, float* __restrict__ stabf){
  int bh = blockIdx.x, t = threadIdx.x;
  float v = (t < 32) ? bmax[bh*32 + t] : -1e30f;
  #pragma unroll
  for (int o = 32; o; o >>= 1) v = fmaxf(v, __shfl_down(v, o));
  if (t == 0) stabf[bh] = v;
}

// Performer K pass 2: K/V staged once per chunk in LDS; thread t owns feature m=t.
__global__ __launch_bounds__(128) void k_ctx2(const float* __restrict__ k, const float* __restrict__ v,
        const float* __restrict__ proj, const float* __restrict__ diag, const float* __restrict__ stabf,
        float* __restrict__ ctxp, float* __restrict__ ksump){
  int bh = blockIdx.x >> 6, chunk = blockIdx.x & 63;
  int b = bh >> 3, h = bh & 7;
  __shared__ float pl[NBF][33];
  __shared__ float kl[128][DH];
  __shared__ float vl[128][DH];
  __shared__ float dg[128];
  int t = threadIdx.x;
  for (int idx = t; idx < NBF*DH; idx += 128){ int m = idx>>5, d = idx&31; pl[m][d] = proj[idx]*F_DN; }
  int i0 = chunk*128;
  for (int idx = t; idx < 128*8; idx += 128){
    int r = idx >> 3, f = idx & 7;
    size_t gofs = (size_t)(b*NTOK + i0 + r)*C + h*DH + f*4;
    *(float4*)&kl[r][f*4] = *(const float4*)(k + gofs);
    *(float4*)&vl[r][f*4] = *(const float4*)(v + gofs);
  }
  dg[t] = diag[bh*NTOK + i0 + t];
  __syncthreads();
  float st = stabf[bh];
  if (t < NBF){
    float acc[DH] = {};
    float ks = 0.f;
    for (int r = 0; r < 128; r++){
      float dd = 0.f;
      #pragma unroll
      for (int d = 0; d < DH; d++) dd += kl[r][d]*pl[t][d];
      float kp = F_RNORM*(expf(dd - dg[r] - st) + 1e-4f);
      ks += kp;
      #pragma unroll
      for (int d = 0; d < DH; d++) acc[d] += kp*vl[r][d];
    }
    size_t base = (((size_t)bh*64 + chunk)*NBF + t)*DH;
    #pragma unroll
    for (int d = 0; d < DH; d++) ctxp[base + d] = acc[d];
    ksump[((size_t)bh*64 + chunk)*NBF + t] = ks;
  }
}

__global__ void k_ctxred(const float* __restrict__ ctxp, const float* __restrict__ ksump,
                         float* __restrict__ ctx, float* __restrict__ ksum){
  int bh = blockIdx.x / NBF, m = blockIdx.x % NBF;
  int t = threadIdx.x;
  if (t < DH){
    float s = 0.f;
    for (int c = 0; c < 64; c++) s += ctxp[(((size_t)bh*64 + c)*NBF + m)*DH + t];
    ctx[((size_t)bh*NBF + m)*DH + t] = s;
  } else if (t == DH){
    float s = 0.f;
    for (int c = 0; c < 64; c++) s += ksump[((size_t)bh*64 + c)*NBF + m];
    ksum[bh*NBF + m] = s;
  }
}

// Performer Q side v2: one block per (bh, 128-row chunk); thread t owns row i0+t.
// proj/ctx/ksum block-resident in LDS (broadcast reads); q rows staged pad-33.
__global__ __launch_bounds__(128) void k_qattn2(const float* __restrict__ q, const float* __restrict__ proj,
        const float* __restrict__ ctx, const float* __restrict__ ksum, ushort* __restrict__ o){
  int bh = blockIdx.x >> 6, chunk = blockIdx.x & 63;
  int b = bh >> 3, h = bh & 7;
  __shared__ float pl[NBF][DH];
  __shared__ float cl[NBF][DH];
  __shared__ float ksl[NBF];
  __shared__ float ql[128][33];
  int t = threadIdx.x;
  for (int idx = t; idx < NBF*DH; idx += 128){
    pl[idx>>5][idx&31] = proj[idx]*F_DN;
    cl[idx>>5][idx&31] = ctx[(size_t)bh*NBF*DH + idx];
  }
  if (t < NBF) ksl[t] = ksum[bh*NBF + t];
  int i0 = chunk*128;
  for (int idx = t; idx < 128*32; idx += 128){
    int r = idx >> 5, c2 = idx & 31;
    ql[r][c2] = q[(size_t)(b*NTOK + i0 + r)*C + h*DH + c2];
  }
  __syncthreads();
  float qv[DH];
  #pragma unroll
  for (int d = 0; d < DH; d++) qv[d] = ql[t][d];
  float sq = 0.f;
  #pragma unroll
  for (int d = 0; d < DH; d++) sq += qv[d]*qv[d];
  float diagv = 0.5f*F_DN*F_DN*sq;
  float mx = -1e30f;
  for (int m = 0; m < NBF; m++){
    float dd = 0.f;
    #pragma unroll
    for (int d = 0; d < DH; d++) dd += qv[d]*pl[m][d];
    mx = fmaxf(mx, dd);
  }
  float og[DH] = {};
  float Dv = 0.f;
  for (int m = 0; m < NBF; m++){
    float dd = 0.f;
    #pragma unroll
    for (int d = 0; d < DH; d++) dd += qv[d]*pl[m][d];
    float qp = F_RNORM*(expf(dd - diagv - mx) + 1e-4f);
    Dv += qp*ksl[m];
    #pragma unroll
    for (int d = 0; d < DH; d++) og[d] += qp*cl[m][d];
  }
  float Dinv = 1.f/Dv;
  ushort* orow = o + (size_t)(b*NTOK + i0 + t)*C + h*DH;
  #pragma unroll
  for (int d = 0; d < DH; d += 2){
    unsigned pk = (unsigned)f2b(og[d]*Dinv) | ((unsigned)f2b(og[d+1]*Dinv) << 16);
    *(unsigned*)(orow + d) = pk;
  }
}

// Local windowed attention, heads 8..15, one wave per (b, hl, window), online softmax.
__global__ __launch_bounds__(64) void k_local(const float* __restrict__ q, const float* __restrict__ k,
        const float* __restrict__ v, ushort* __restrict__ o){
  int blk = blockIdx.x;
  int w = blk & (NW-1);
  int rem = blk >> 7;
  int hl = rem & 7, b = rem >> 3;
  int hd = GH + hl;
  __shared__ float kl[3*WIN][DH];
  __shared__ float vl[3*WIN][DH];
  int t = threadIdx.x;
  int jstart = (w == 0) ? WIN : 0;
  int jend   = (w == NW-1) ? 2*WIN : 3*WIN;
  int nrows = jend - jstart;
  for (int idx = t; idx < nrows*DH; idx += 64){
    int j = jstart + (idx >> 5), d = idx & 31;
    int pos = (w-1)*WIN + j;
    size_t gidx = (size_t)(b*NTOK + pos)*C + hd*DH + d;
    kl[j][d] = k[gidx];
    vl[j][d] = v[gidx];
  }
  __syncthreads();
  size_t qg = (size_t)(b*NTOK + w*WIN + t)*C + hd*DH;
  float qreg[DH];
  #pragma unroll
  for (int d = 0; d < DH; d++) qreg[d] = q[qg + d]*F_LSCALE;
  float mx = -1e30f, l = 0.f;
  float acc[DH] = {};
  for (int j = jstart; j < jend; j++){
    float s = 0.f;
    #pragma unroll
    for (int d = 0; d < DH; d++) s += qreg[d]*kl[j][d];
    float nm = fmaxf(mx, s);
    float corr = expf(mx - nm);
    float pexp = expf(s - nm);
    l = l*corr + pexp;
    #pragma unroll
    for (int d = 0; d < DH; d++) acc[d] = acc[d]*corr + pexp*vl[j][d];
    mx = nm;
  }
  float inv = 1.f/l;
  #pragma unroll
  for (int d = 0; d < DH; d++) o[qg + d] = f2b(acc[d]*inv);
}

} // namespace

extern "C" void kernel_launch(void* const* d_in, const int* in_sizes, int n_in,
                              void* d_out, int out_size, void* d_ws, size_t ws_size,
                              hipStream_t stream){
  (void)in_sizes; (void)n_in; (void)out_size; (void)ws_size;
  const float* x     = (const float*)d_in[0];
  const float* ln1_g = (const float*)d_in[1];
  const float* ln1_b = (const float*)d_in[2];
  const float* Wq    = (const float*)d_in[3];
  const float* bq    = (const float*)d_in[4];
  const float* Wk    = (const float*)d_in[5];
  const float* bk    = (const float*)d_in[6];
  const float* Wv    = (const float*)d_in[7];
  const float* bv    = (const float*)d_in[8];
  const float* Wo    = (const float*)d_in[9];
  const float* bo    = (const float*)d_in[10];
  const float* proj  = (const float*)d_in[11];
  const float* ln2_g = (const float*)d_in[12];
  const float* ln2_b = (const float*)d_in[13];
  const float* W1    = (const float*)d_in[14];
  const float* b1    = (const float*)d_in[15];
  const float* W2    = (const float*)d_in[16];
  const float* b2    = (const float*)d_in[17];

  float* h = (float*)d_out;
  const size_t MC = (size_t)MROWS*C;
  char* w = (char*)d_ws;
  auto alloc = [&](size_t bytes)->char*{ char* p = w; w += (bytes + 255) & ~(size_t)255; return p; };

  ushort* y16  = (ushort*)alloc(MC*2);
  float*  qb   = (float*) alloc(MC*4);
  float*  kb   = (float*) alloc(MC*4);
  float*  vb   = (float*) alloc(MC*4);
  ushort* o16  = (ushort*)alloc(MC*2);
  ushort* wt   = (ushort*)alloc((size_t)2097152*2);   // per-layer transposed bf16 weights
  float*  cost = (float*) alloc((size_t)NTOK*16*4);
  float*  sint = (float*) alloc((size_t)NTOK*16*4);
  float*  diag = (float*) alloc((size_t)16*NTOK*4);
  float*  bmax = (float*) alloc(16*32*4);
  float*  stabf= (float*) alloc(16*4);
  float*  ctxb = (float*) alloc((size_t)16*NBF*DH*4);
  float*  ksum = (float*) alloc((size_t)16*NBF*4);

  ushort* mid16 = (ushort*)qb;             // FFN intermediate (M*FF bf16 = 33.6MB) aliases q (dead)
  float*  ctxp  = (float*)o16;             // ctx partials (14.4MB) alias o16 (written later)
  float*  ksump = ctxp + (size_t)16*64*NBF*DH;

  ushort* wtq = wt;
  ushort* wtk = wt +  262144;
  ushort* wtv = wt +  524288;
  ushort* wto = wt +  786432;
  ushort* wt1 = wt + 1048576;
  ushort* wt2 = wt + 1572864;

  k_tables<<<(NTOK*16 + 255)/256, 256, 0, stream>>>(cost, sint);
  k_copy<<<(int)((MC/4 + 255)/256), 256, 0, stream>>>((const float4*)x, (float4*)h, (int)(MC/4));

  dim3 blk(256);
  dim3 g512(4, 128);    // N=512
  dim3 gff(8, 128);     // N=1024

  for (int l = 0; l < 2; l++){
    const float* pj = proj + (size_t)l*NBF*DH;
    k_wcvt<<<dim3(16,16), blk, 0, stream>>>(Wq + (size_t)l*C*C,  wtq, C, C);
    k_wcvt<<<dim3(16,16), blk, 0, stream>>>(Wk + (size_t)l*C*C,  wtk, C, C);
    k_wcvt<<<dim3(16,16), blk, 0, stream>>>(Wv + (size_t)l*C*C,  wtv, C, C);
    k_wcvt<<<dim3(16,16), blk, 0, stream>>>(Wo + (size_t)l*C*C,  wto, C, C);
    k_wcvt<<<dim3(32,16), blk, 0, stream>>>(W1 + (size_t)l*C*FF, wt1, C, FF);
    k_wcvt<<<dim3(16,32), blk, 0, stream>>>(W2 + (size_t)l*FF*C, wt2, FF, C);

    k_ln<<<MROWS, 256, 0, stream>>>(h, ln1_g + l*C, ln1_b + l*C, y16);
    k_mgemm<0,0><<<g512, blk, 0, stream>>>(y16, wtq, bq + l*C, nullptr, qb, nullptr, C, C);
    k_mgemm<0,0><<<g512, blk, 0, stream>>>(y16, wtk, bk + l*C, nullptr, kb, nullptr, C, C);
    k_mgemm<0,0><<<g512, blk, 0, stream>>>(y16, wtv, bv + l*C, nullptr, vb, nullptr, C, C);
    k_rope<<<(MROWS*128)/256, 256, 0, stream>>>(qb, kb, cost, sint);
    k_kpre<<<16*32, 256, 0, stream>>>(kb, pj, diag, bmax);
    k_redmax<<<16, 64, 0, stream>>>(bmax, stabf);
    k_ctx2<<<16*64, 128, 0, stream>>>(kb, vb, pj, diag, stabf, ctxp, ksump);
    k_ctxred<<<16*NBF, 64, 0, stream>>>(ctxp, ksump, ctxb, ksum);
    k_qattn2<<<16*64, 128, 0, stream>>>(qb, pj, ctxb, ksum, o16);
    k_local<<<BATCH*8*NW, 64, 0, stream>>>(qb, kb, vb, o16);
    k_mgemm<0,0><<<g512, blk, 0, stream>>>(o16, wto, bo + l*C, h, h, nullptr, C, C);
    k_ln<<<MROWS, 256, 0, stream>>>(h, ln2_g + l*C, ln2_b + l*C, y16);
    k_mgemm<1,1><<<gff, blk, 0, stream>>>(y16, wt1, b1 + l*FF, nullptr, nullptr, mid16, FF, C);
    k_mgemm<0,0><<<g512, blk, 0, stream>>>(mid16, wt2, b2 + l*C, h, h, nullptr, C, FF);
  }
}

// Round 4
// 1230.091 us; speedup vs baseline: 5.8995x; 1.1084x over previous
//
#include <hip/hip_runtime.h>
#include <math.h>

namespace {

constexpr int BATCH = 2;
constexpr int NTOK  = 8192;    // tokens per batch (T*H*W)
constexpr int MROWS = 16384;   // BATCH*NTOK
constexpr int C     = 512;
constexpr int GH    = 8;
constexpr int DH    = 32;
constexpr int WIN   = 64;
constexpr int NW    = 128;     // NTOK/WIN
constexpr int FF    = 1024;
constexpr int NBF   = 110;     // int(32*ln(32))

constexpr float F_DN     = 0.42044820762685725f;   // 32^-0.25
constexpr float F_RNORM  = 0.09534625892455924f;   // 110^-0.5
constexpr float F_LSCALE = 0.17677669529663687f;   // 32^-0.5

typedef __attribute__((ext_vector_type(8))) short bf16x8;
typedef __attribute__((ext_vector_type(4))) float f32x4;

__device__ __forceinline__ ushort f2b(float f){
  unsigned u = __float_as_uint(f);
  unsigned r = u + 0x7FFFu + ((u >> 16) & 1u);
  return (ushort)(r >> 16);
}
__device__ __forceinline__ float b2f(ushort u){
  return __uint_as_float((unsigned)u << 16);
}
__device__ __forceinline__ void unpk(unsigned u, float& a, float& b){
  a = __uint_as_float(u << 16);
  b = __uint_as_float(u & 0xffff0000u);
}

__device__ __forceinline__ void gload16(const void* g, void* l){
  __builtin_amdgcn_global_load_lds((const __attribute__((address_space(1))) void*)g,
                                   (__attribute__((address_space(3))) void*)l, 16, 0, 0);
}

__global__ void k_tables(float* __restrict__ cost, float* __restrict__ sint){
  int idx = blockIdx.x*256 + threadIdx.x;
  if (idx >= NTOK*16) return;
  int pos = idx >> 4, f = idx & 15;
  float inv = powf(10000.f, -(float)f/16.f);
  float ang = (float)pos * inv;
  cost[idx] = cosf(ang);
  sint[idx] = sinf(ang);
}

__global__ void k_copy(const float4* __restrict__ s, float4* __restrict__ d, int n){
  int i = blockIdx.x*256 + threadIdx.x;
  if (i < n) d[i] = s[i];
}

// fp32 (K,N) -> bf16 transposed (N,K)
__global__ __launch_bounds__(256) void k_wcvt(const float* __restrict__ W, ushort* __restrict__ Wt,
                                              int K, int N){
  __shared__ float t[32][33];
  int bx = blockIdx.x, by = blockIdx.y;
  int tx = threadIdx.x & 31, ty = threadIdx.x >> 5;
  #pragma unroll
  for (int r = ty; r < 32; r += 8) t[r][tx] = W[(size_t)(by*32+r)*N + bx*32 + tx];
  __syncthreads();
  #pragma unroll
  for (int r = ty; r < 32; r += 8) Wt[(size_t)(bx*32+r)*K + by*32 + tx] = f2b(t[tx][r]);
}

__global__ __launch_bounds__(256) void k_ln(const float* __restrict__ x, const float* __restrict__ g,
                     const float* __restrict__ b, ushort* __restrict__ y){
  int row = blockIdx.x, t = threadIdx.x;
  const float* xr = x + (size_t)row*C;
  float2 v = *(const float2*)(xr + 2*t);
  float s = v.x + v.y, ss = v.x*v.x + v.y*v.y;
  #pragma unroll
  for (int o = 32; o; o >>= 1){ s += __shfl_down(s, o); ss += __shfl_down(ss, o); }
  __shared__ float rs[4], rss[4];
  int wv = t >> 6, ln = t & 63;
  if (ln == 0){ rs[wv] = s; rss[wv] = ss; }
  __syncthreads();
  float S = rs[0]+rs[1]+rs[2]+rs[3], SS = rss[0]+rss[1]+rss[2]+rss[3];
  float mean = S * (1.f/C);
  float var  = SS * (1.f/C) - mean*mean;
  float rstd = rsqrtf(var + 1e-5f);
  float2 gg = *(const float2*)(g + 2*t);
  float2 bb = *(const float2*)(b + 2*t);
  ushort2 ov;
  ov.x = f2b((v.x - mean)*rstd*gg.x + bb.x);
  ov.y = f2b((v.y - mean)*rstd*gg.y + bb.y);
  *(ushort2*)(y + (size_t)row*C + 2*t) = ov;
}

// bf16 MFMA GEMM, m97 structure: out = ACT(A@B + bias) (+res)
// A: (M,K) bf16 row-major.  Bt: (N,K) bf16 row-major (i.e. B^T).
// grid (Nd/128, M/128), 256 threads (4 waves, 2x2 of 64x64).
template<int ACT, int OBF>
__global__ __launch_bounds__(256) void k_mgemm(const ushort* __restrict__ A, const ushort* __restrict__ Bt,
      const float* __restrict__ bias, const float* __restrict__ res,
      float* __restrict__ outf, ushort* __restrict__ outb, int Nd, int Kd){
  __shared__ ushort As[128*32];
  __shared__ ushort Bs[128*32];
  int tid = threadIdx.x;
  int lane = tid & 63, wave = tid >> 6;
  int wr = wave >> 1, wc = wave & 1;
  int row0 = blockIdx.y*128, col0 = blockIdx.x*128;
  f32x4 acc[4][4] = {};
  for (int k0 = 0; k0 < Kd; k0 += 32){
    __syncthreads();
    #pragma unroll
    for (int c = 0; c < 2; c++){
      int off = (wave*2 + c)*1024 + lane*16;       // byte offset in 8KB tile
      int r = off >> 6, ke = (off & 63) >> 1;      // row, k-element
      gload16(A  + (size_t)(row0 + r)*Kd + k0 + ke, (char*)As + (wave*2 + c)*1024);
      gload16(Bt + (size_t)(col0 + r)*Kd + k0 + ke, (char*)Bs + (wave*2 + c)*1024);
    }
    __syncthreads();
    bf16x8 af[4], bfr[4];
    #pragma unroll
    for (int m = 0; m < 4; m++)
      af[m] = *(const bf16x8*)((const char*)As + (wr*64 + m*16 + (lane&15))*64 + (lane>>4)*16);
    #pragma unroll
    for (int n = 0; n < 4; n++)
      bfr[n] = *(const bf16x8*)((const char*)Bs + (wc*64 + n*16 + (lane&15))*64 + (lane>>4)*16);
    #pragma unroll
    for (int m = 0; m < 4; m++)
      #pragma unroll
      for (int n = 0; n < 4; n++)
        acc[m][n] = __builtin_amdgcn_mfma_f32_16x16x32_bf16(af[m], bfr[n], acc[m][n], 0, 0, 0);
  }
  #pragma unroll
  for (int m = 0; m < 4; m++){
    int rbase = row0 + wr*64 + m*16 + (lane>>4)*4;
    #pragma unroll
    for (int n = 0; n < 4; n++){
      int ccol = col0 + wc*64 + n*16 + (lane&15);
      float bv = bias[ccol];
      #pragma unroll
      for (int r = 0; r < 4; r++){
        int grow = rbase + r;
        float vv = acc[m][n][r] + bv;
        if (ACT == 1) vv = 0.5f*vv*(1.f + erff(vv*0.7071067811865476f));
        if (res) vv += res[(size_t)grow*Nd + ccol];
        if (OBF) outb[(size_t)grow*Nd + ccol] = f2b(vv);
        else     outf[(size_t)grow*Nd + ccol] = vv;
      }
    }
  }
}

// RoPE in place on bf16 local-head channels [256,512) of q and k. One thread per (row, head).
__global__ __launch_bounds__(256) void k_rope16(ushort* __restrict__ q, ushort* __restrict__ k,
                       const float* __restrict__ cost, const float* __restrict__ sint){
  int idx = blockIdx.x*256 + threadIdx.x;
  if (idx >= MROWS*8) return;
  int r = idx >> 3, head = idx & 7;
  int pos = r & (NTOK-1);
  size_t base = (size_t)r*C + 256 + head*32;
  ushort qv[32], kv[32];
  *(uint4*)(qv)    = *(const uint4*)(q+base);
  *(uint4*)(qv+8)  = *(const uint4*)(q+base+8);
  *(uint4*)(qv+16) = *(const uint4*)(q+base+16);
  *(uint4*)(qv+24) = *(const uint4*)(q+base+24);
  *(uint4*)(kv)    = *(const uint4*)(k+base);
  *(uint4*)(kv+8)  = *(const uint4*)(k+base+8);
  *(uint4*)(kv+16) = *(const uint4*)(k+base+16);
  *(uint4*)(kv+24) = *(const uint4*)(k+base+24);
  #pragma unroll
  for (int d = 0; d < 16; d++){
    float cv = cost[pos*16+d], sv = sint[pos*16+d];
    float a = b2f(qv[d]), b2 = b2f(qv[d+16]);
    qv[d]    = f2b(a*cv - b2*sv);
    qv[d+16] = f2b(b2*cv + a*sv);
    float ka = b2f(kv[d]), kb2 = b2f(kv[d+16]);
    kv[d]    = f2b(ka*cv - kb2*sv);
    kv[d+16] = f2b(kb2*cv + ka*sv);
  }
  *(uint4*)(q+base)    = *(uint4*)(qv);
  *(uint4*)(q+base+8)  = *(uint4*)(qv+8);
  *(uint4*)(q+base+16) = *(uint4*)(qv+16);
  *(uint4*)(q+base+24) = *(uint4*)(qv+24);
  *(uint4*)(k+base)    = *(uint4*)(kv);
  *(uint4*)(k+base+8)  = *(uint4*)(kv+8);
  *(uint4*)(k+base+16) = *(uint4*)(kv+16);
  *(uint4*)(k+base+24) = *(uint4*)(kv+24);
}

// Performer K pre-pass: per-row diag + per-(bh,chunk) max of dd. No atomics.
__global__ __launch_bounds__(256) void k_kpre(const ushort* __restrict__ k, const float* __restrict__ proj,
        float* __restrict__ diag, float* __restrict__ bmax){
  int bh = blockIdx.x >> 5, chunk = blockIdx.x & 31;
  int b = bh >> 3, h = bh & 7;
  __shared__ float pl[NBF][DH];
  int t = threadIdx.x;
  for (int idx = t; idx < NBF*DH; idx += 256) pl[idx>>5][idx&31] = proj[idx]*F_DN;
  __syncthreads();
  int i = chunk*256 + t;
  const ushort* kr = k + (size_t)(b*NTOK + i)*C + h*DH;
  ushort kt[32];
  *(uint4*)(kt)    = *(const uint4*)(kr);
  *(uint4*)(kt+8)  = *(const uint4*)(kr+8);
  *(uint4*)(kt+16) = *(const uint4*)(kr+16);
  *(uint4*)(kt+24) = *(const uint4*)(kr+24);
  float kv[DH];
  #pragma unroll
  for (int d = 0; d < DH; d++) kv[d] = b2f(kt[d]);
  float sq = 0.f;
  #pragma unroll
  for (int d = 0; d < DH; d++) sq += kv[d]*kv[d];
  diag[bh*NTOK + i] = 0.5f*F_DN*F_DN*sq;
  float mx = -1e30f;
  for (int m = 0; m < NBF; m++){
    float a = 0.f;
    #pragma unroll
    for (int d = 0; d < DH; d++) a += kv[d]*pl[m][d];
    mx = fmaxf(mx, a);
  }
  #pragma unroll
  for (int o = 32; o; o >>= 1) mx = fmaxf(mx, __shfl_down(mx, o));
  __shared__ float red[4];
  if ((t & 63) == 0) red[t>>6] = mx;
  __syncthreads();
  if (t == 0) bmax[bh*32 + chunk] = fmaxf(fmaxf(red[0],red[1]), fmaxf(red[2],red[3]));
}

__global__ void k_redmax(const float* __restrict__ bmax, float* __restrict__ stabf){
  int bh = blockIdx.x, t = threadIdx.x;
  float v = (t < 32) ? bmax[bh*32 + t] : -1e30f;
  #pragma unroll
  for (int o = 32; o; o >>= 1) v = fmaxf(v, __shfl_down(v, o));
  if (t == 0) stabf[bh] = v;
}

// Performer K pass 2: K/V staged once per chunk in LDS (fp32); thread t owns feature m=t.
__global__ __launch_bounds__(128) void k_ctx2(const ushort* __restrict__ k, const ushort* __restrict__ v,
        const float* __restrict__ proj, const float* __restrict__ diag, const float* __restrict__ stabf,
        float* __restrict__ ctxp, float* __restrict__ ksump){
  int bh = blockIdx.x >> 6, chunk = blockIdx.x & 63;
  int b = bh >> 3, h = bh & 7;
  __shared__ float pl[NBF][33];
  __shared__ float kl[128][DH];
  __shared__ float vl[128][DH];
  __shared__ float dg[128];
  int t = threadIdx.x;
  for (int idx = t; idx < NBF*DH; idx += 128){ int m = idx>>5, d = idx&31; pl[m][d] = proj[idx]*F_DN; }
  int i0 = chunk*128;
  for (int idx = t; idx < 128*4; idx += 128){
    int r = idx >> 2, f = idx & 3;
    size_t gofs = (size_t)(b*NTOK + i0 + r)*C + h*DH + f*8;
    uint4 kk = *(const uint4*)(k + gofs);
    uint4 vv = *(const uint4*)(v + gofs);
    float a, b2;
    unpk(kk.x,a,b2); kl[r][f*8+0]=a; kl[r][f*8+1]=b2;
    unpk(kk.y,a,b2); kl[r][f*8+2]=a; kl[r][f*8+3]=b2;
    unpk(kk.z,a,b2); kl[r][f*8+4]=a; kl[r][f*8+5]=b2;
    unpk(kk.w,a,b2); kl[r][f*8+6]=a; kl[r][f*8+7]=b2;
    unpk(vv.x,a,b2); vl[r][f*8+0]=a; vl[r][f*8+1]=b2;
    unpk(vv.y,a,b2); vl[r][f*8+2]=a; vl[r][f*8+3]=b2;
    unpk(vv.z,a,b2); vl[r][f*8+4]=a; vl[r][f*8+5]=b2;
    unpk(vv.w,a,b2); vl[r][f*8+6]=a; vl[r][f*8+7]=b2;
  }
  dg[t] = diag[bh*NTOK + i0 + t];
  __syncthreads();
  float st = stabf[bh];
  if (t < NBF){
    float acc[DH] = {};
    float ks = 0.f;
    for (int r = 0; r < 128; r++){
      float dd = 0.f;
      #pragma unroll
      for (int d = 0; d < DH; d++) dd += kl[r][d]*pl[t][d];
      float kp = F_RNORM*(expf(dd - dg[r] - st) + 1e-4f);
      ks += kp;
      #pragma unroll
      for (int d = 0; d < DH; d++) acc[d] += kp*vl[r][d];
    }
    size_t base = (((size_t)bh*64 + chunk)*NBF + t)*DH;
    #pragma unroll
    for (int d = 0; d < DH; d++) ctxp[base + d] = acc[d];
    ksump[((size_t)bh*64 + chunk)*NBF + t] = ks;
  }
}

__global__ void k_ctxred(const float* __restrict__ ctxp, const float* __restrict__ ksump,
                         float* __restrict__ ctx, float* __restrict__ ksum){
  int bh = blockIdx.x / NBF, m = blockIdx.x % NBF;
  int t = threadIdx.x;
  if (t < DH){
    float s = 0.f;
    for (int c = 0; c < 64; c++) s += ctxp[(((size_t)bh*64 + c)*NBF + m)*DH + t];
    ctx[((size_t)bh*NBF + m)*DH + t] = s;
  } else if (t == DH){
    float s = 0.f;
    for (int c = 0; c < 64; c++) s += ksump[((size_t)bh*64 + c)*NBF + m];
    ksum[bh*NBF + m] = s;
  }
}

// Performer Q side v2: one block per (bh, 128-row chunk); thread t owns row i0+t.
__global__ __launch_bounds__(128) void k_qattn2(const ushort* __restrict__ q, const float* __restrict__ proj,
        const float* __restrict__ ctx, const float* __restrict__ ksum, ushort* __restrict__ o){
  int bh = blockIdx.x >> 6, chunk = blockIdx.x & 63;
  int b = bh >> 3, h = bh & 7;
  __shared__ float pl[NBF][DH];
  __shared__ float cl[NBF][DH];
  __shared__ float ksl[NBF];
  __shared__ float ql[128][33];
  int t = threadIdx.x;
  for (int idx = t; idx < NBF*DH; idx += 128){
    pl[idx>>5][idx&31] = proj[idx]*F_DN;
    cl[idx>>5][idx&31] = ctx[(size_t)bh*NBF*DH + idx];
  }
  if (t < NBF) ksl[t] = ksum[bh*NBF + t];
  int i0 = chunk*128;
  for (int idx = t; idx < 128*4; idx += 128){
    int r = idx >> 2, f = idx & 3;
    uint4 qq = *(const uint4*)(q + (size_t)(b*NTOK + i0 + r)*C + h*DH + f*8);
    float a, b2;
    unpk(qq.x,a,b2); ql[r][f*8+0]=a; ql[r][f*8+1]=b2;
    unpk(qq.y,a,b2); ql[r][f*8+2]=a; ql[r][f*8+3]=b2;
    unpk(qq.z,a,b2); ql[r][f*8+4]=a; ql[r][f*8+5]=b2;
    unpk(qq.w,a,b2); ql[r][f*8+6]=a; ql[r][f*8+7]=b2;
  }
  __syncthreads();
  float qv[DH];
  #pragma unroll
  for (int d = 0; d < DH; d++) qv[d] = ql[t][d];
  float sq = 0.f;
  #pragma unroll
  for (int d = 0; d < DH; d++) sq += qv[d]*qv[d];
  float diagv = 0.5f*F_DN*F_DN*sq;
  float mx = -1e30f;
  for (int m = 0; m < NBF; m++){
    float dd = 0.f;
    #pragma unroll
    for (int d = 0; d < DH; d++) dd += qv[d]*pl[m][d];
    mx = fmaxf(mx, dd);
  }
  float og[DH] = {};
  float Dv = 0.f;
  for (int m = 0; m < NBF; m++){
    float dd = 0.f;
    #pragma unroll
    for (int d = 0; d < DH; d++) dd += qv[d]*pl[m][d];
    float qp = F_RNORM*(expf(dd - diagv - mx) + 1e-4f);
    Dv += qp*ksl[m];
    #pragma unroll
    for (int d = 0; d < DH; d++) og[d] += qp*cl[m][d];
  }
  float Dinv = 1.f/Dv;
  ushort* orow = o + (size_t)(b*NTOK + i0 + t)*C + h*DH;
  #pragma unroll
  for (int d = 0; d < DH; d += 2){
    unsigned pk = (unsigned)f2b(og[d]*Dinv) | ((unsigned)f2b(og[d+1]*Dinv) << 16);
    *(unsigned*)(orow + d) = pk;
  }
}

// Local windowed attention, bf16 K/V in LDS, no-stab single-pass softmax
// (scores are O(1): softmax shift-invariance makes max-subtraction unnecessary).
__global__ __launch_bounds__(64) void k_local(const ushort* __restrict__ q, const ushort* __restrict__ k,
        const ushort* __restrict__ v, ushort* __restrict__ o){
  int blk = blockIdx.x;
  int w = blk & (NW-1);
  int rem = blk >> 7;
  int hl = rem & 7, b = rem >> 3;
  int hd = GH + hl;
  __shared__ ushort kl[3*WIN*DH];   // 12KB
  __shared__ ushort vl[3*WIN*DH];   // 12KB
  int t = threadIdx.x;
  {
    const char* kg = (const char*)(k + (size_t)(b*NTOK + (w-1)*WIN)*C + hd*DH);
    const char* vg = (const char*)(v + (size_t)(b*NTOK + (w-1)*WIN)*C + hd*DH);
    int f = t*16;
    #pragma unroll
    for (int c = 0; c < 12; c++){
      int row = f >> 6, col = f & 63;
      size_t gofs = (size_t)row*(C*2) + col;
      gload16(kg + gofs, (char*)kl + c*1024);
      gload16(vg + gofs, (char*)vl + c*1024);
      f += 1024;
    }
  }
  asm volatile("s_waitcnt vmcnt(0)" ::: "memory");
  __syncthreads();
  size_t qg = (size_t)(b*NTOK + w*WIN + t)*C + hd*DH;
  ushort qt[32];
  *(uint4*)(qt)    = *(const uint4*)(q+qg);
  *(uint4*)(qt+8)  = *(const uint4*)(q+qg+8);
  *(uint4*)(qt+16) = *(const uint4*)(q+qg+16);
  *(uint4*)(qt+24) = *(const uint4*)(q+qg+24);
  float qreg[DH];
  #pragma unroll
  for (int d = 0; d < DH; d++) qreg[d] = b2f(qt[d])*F_LSCALE;
  int jstart = (w == 0) ? WIN : 0;
  int jend   = (w == NW-1) ? 2*WIN : 3*WIN;
  float l = 0.f;
  float acc[DH] = {};
  for (int j = jstart; j < jend; j++){
    unsigned kw[16], vw[16];
    const ushort* klr = kl + j*DH;
    const ushort* vlr = vl + j*DH;
    *(uint4*)(kw)    = *(const uint4*)(klr);
    *(uint4*)(kw+4)  = *(const uint4*)(klr+8);
    *(uint4*)(kw+8)  = *(const uint4*)(klr+16);
    *(uint4*)(kw+12) = *(const uint4*)(klr+24);
    *(uint4*)(vw)    = *(const uint4*)(vlr);
    *(uint4*)(vw+4)  = *(const uint4*)(vlr+8);
    *(uint4*)(vw+8)  = *(const uint4*)(vlr+16);
    *(uint4*)(vw+12) = *(const uint4*)(vlr+24);
    float sp0=0.f, sp1=0.f, sp2=0.f, sp3=0.f;
    #pragma unroll
    for (int u = 0; u < 16; u += 4){
      float a, b2;
      unpk(kw[u],  a, b2); sp0 = fmaf(qreg[2*u],   a, sp0); sp1 = fmaf(qreg[2*u+1], b2, sp1);
      unpk(kw[u+1],a, b2); sp2 = fmaf(qreg[2*u+2], a, sp2); sp3 = fmaf(qreg[2*u+3], b2, sp3);
      unpk(kw[u+2],a, b2); sp0 = fmaf(qreg[2*u+4], a, sp0); sp1 = fmaf(qreg[2*u+5], b2, sp1);
      unpk(kw[u+3],a, b2); sp2 = fmaf(qreg[2*u+6], a, sp2); sp3 = fmaf(qreg[2*u+7], b2, sp3);
    }
    float p = __expf((sp0+sp1) + (sp2+sp3));
    l += p;
    #pragma unroll
    for (int u = 0; u < 16; u++){
      float a, b2;
      unpk(vw[u], a, b2);
      acc[2*u]   = fmaf(p, a,  acc[2*u]);
      acc[2*u+1] = fmaf(p, b2, acc[2*u+1]);
    }
  }
  float inv = 1.f/l;
  ushort ot[32];
  #pragma unroll
  for (int d = 0; d < DH; d++) ot[d] = f2b(acc[d]*inv);
  *(uint4*)(o+qg)    = *(uint4*)(ot);
  *(uint4*)(o+qg+8)  = *(uint4*)(ot+8);
  *(uint4*)(o+qg+16) = *(uint4*)(ot+16);
  *(uint4*)(o+qg+24) = *(uint4*)(ot+24);
}

} // namespace

extern "C" void kernel_launch(void* const* d_in, const int* in_sizes, int n_in,
                              void* d_out, int out_size, void* d_ws, size_t ws_size,
                              hipStream_t stream){
  (void)in_sizes; (void)n_in; (void)out_size; (void)ws_size;
  const float* x     = (const float*)d_in[0];
  const float* ln1_g = (const float*)d_in[1];
  const float* ln1_b = (const float*)d_in[2];
  const float* Wq    = (const float*)d_in[3];
  const float* bq    = (const float*)d_in[4];
  const float* Wk    = (const float*)d_in[5];
  const float* bk    = (const float*)d_in[6];
  const float* Wv    = (const float*)d_in[7];
  const float* bv    = (const float*)d_in[8];
  const float* Wo    = (const float*)d_in[9];
  const float* bo    = (const float*)d_in[10];
  const float* proj  = (const float*)d_in[11];
  const float* ln2_g = (const float*)d_in[12];
  const float* ln2_b = (const float*)d_in[13];
  const float* W1    = (const float*)d_in[14];
  const float* b1    = (const float*)d_in[15];
  const float* W2    = (const float*)d_in[16];
  const float* b2    = (const float*)d_in[17];

  float* h = (float*)d_out;
  const size_t MC = (size_t)MROWS*C;
  char* w = (char*)d_ws;
  auto alloc = [&](size_t bytes)->char*{ char* p = w; w += (bytes + 255) & ~(size_t)255; return p; };

  ushort* y16  = (ushort*)alloc(MC*2);
  ushort* qb16 = (ushort*)alloc(MC*2);   // order matters: k_local stages with +-64KB overread
  ushort* kb16 = (ushort*)alloc(MC*2);
  ushort* vb16 = (ushort*)alloc(MC*2);
  ushort* o16  = (ushort*)alloc(MC*2);
  ushort* wt   = (ushort*)alloc((size_t)2097152*2);   // per-layer transposed bf16 weights
  float*  cost = (float*) alloc((size_t)NTOK*16*4);
  float*  sint = (float*) alloc((size_t)NTOK*16*4);
  float*  diag = (float*) alloc((size_t)16*NTOK*4);
  float*  bmax = (float*) alloc(16*32*4);
  float*  stabf= (float*) alloc(16*4);
  float*  ctxb = (float*) alloc((size_t)16*NBF*DH*4);
  float*  ksum = (float*) alloc((size_t)16*NBF*4);

  ushort* mid16 = qb16;                    // FFN mid (M*FF bf16 = 32MB) aliases qb16+kb16 (dead)
  float*  ctxp  = (float*)o16;             // ctx partials (14.4MB) alias o16 (written later)
  float*  ksump = ctxp + (size_t)16*64*NBF*DH;

  ushort* wtq = wt;
  ushort* wtk = wt +  262144;
  ushort* wtv = wt +  524288;
  ushort* wto = wt +  786432;
  ushort* wt1 = wt + 1048576;
  ushort* wt2 = wt + 1572864;

  k_tables<<<(NTOK*16 + 255)/256, 256, 0, stream>>>(cost, sint);
  k_copy<<<(int)((MC/4 + 255)/256), 256, 0, stream>>>((const float4*)x, (float4*)h, (int)(MC/4));

  dim3 blk(256);
  dim3 g512(4, 128);    // N=512
  dim3 gff(8, 128);     // N=1024

  for (int l = 0; l < 2; l++){
    const float* pj = proj + (size_t)l*NBF*DH;
    k_wcvt<<<dim3(16,16), blk, 0, stream>>>(Wq + (size_t)l*C*C,  wtq, C, C);
    k_wcvt<<<dim3(16,16), blk, 0, stream>>>(Wk + (size_t)l*C*C,  wtk, C, C);
    k_wcvt<<<dim3(16,16), blk, 0, stream>>>(Wv + (size_t)l*C*C,  wtv, C, C);
    k_wcvt<<<dim3(16,16), blk, 0, stream>>>(Wo + (size_t)l*C*C,  wto, C, C);
    k_wcvt<<<dim3(32,16), blk, 0, stream>>>(W1 + (size_t)l*C*FF, wt1, C, FF);
    k_wcvt<<<dim3(16,32), blk, 0, stream>>>(W2 + (size_t)l*FF*C, wt2, FF, C);

    k_ln<<<MROWS, 256, 0, stream>>>(h, ln1_g + l*C, ln1_b + l*C, y16);
    k_mgemm<0,1><<<g512, blk, 0, stream>>>(y16, wtq, bq + l*C, nullptr, nullptr, qb16, C, C);
    k_mgemm<0,1><<<g512, blk, 0, stream>>>(y16, wtk, bk + l*C, nullptr, nullptr, kb16, C, C);
    k_mgemm<0,1><<<g512, blk, 0, stream>>>(y16, wtv, bv + l*C, nullptr, nullptr, vb16, C, C);
    k_rope16<<<(MROWS*8 + 255)/256, 256, 0, stream>>>(qb16, kb16, cost, sint);
    k_kpre<<<16*32, 256, 0, stream>>>(kb16, pj, diag, bmax);
    k_redmax<<<16, 64, 0, stream>>>(bmax, stabf);
    k_ctx2<<<16*64, 128, 0, stream>>>(kb16, vb16, pj, diag, stabf, ctxp, ksump);
    k_ctxred<<<16*NBF, 64, 0, stream>>>(ctxp, ksump, ctxb, ksum);
    k_qattn2<<<16*64, 128, 0, stream>>>(qb16, pj, ctxb, ksum, o16);
    k_local<<<BATCH*8*NW, 64, 0, stream>>>(qb16, kb16, vb16, o16);
    k_mgemm<0,0><<<g512, blk, 0, stream>>>(o16, wto, bo + l*C, h, h, nullptr, C, C);
    k_ln<<<MROWS, 256, 0, stream>>>(h, ln2_g + l*C, ln2_b + l*C, y16);
    k_mgemm<1,1><<<gff, blk, 0, stream>>>(y16, wt1, b1 + l*FF, nullptr, nullptr, mid16, FF, C);
    k_mgemm<0,0><<<g512, blk, 0, stream>>>(mid16, wt2, b2 + l*C, h, h, nullptr, C, FF);
  }
}

// Round 5
// 974.083 us; speedup vs baseline: 7.4500x; 1.2628x over previous
//
#include <hip/hip_runtime.h>
#include <math.h>

namespace {

constexpr int BATCH = 2;
constexpr int NTOK  = 8192;    // tokens per batch (T*H*W)
constexpr int MROWS = 16384;   // BATCH*NTOK
constexpr int C     = 512;
constexpr int GH    = 8;
constexpr int DH    = 32;
constexpr int WIN   = 64;
constexpr int NW    = 128;     // NTOK/WIN
constexpr int FF    = 1024;
constexpr int NBF   = 110;     // int(32*ln(32))

constexpr float F_DN     = 0.42044820762685725f;   // 32^-0.25
constexpr float F_RNORM  = 0.09534625892455924f;   // 110^-0.5
constexpr float F_LSCALE = 0.17677669529663687f;   // 32^-0.5

typedef __attribute__((ext_vector_type(8))) short bf16x8;
typedef __attribute__((ext_vector_type(4))) float f32x4;

__device__ __forceinline__ ushort f2b(float f){
  unsigned u = __float_as_uint(f);
  unsigned r = u + 0x7FFFu + ((u >> 16) & 1u);
  return (ushort)(r >> 16);
}
__device__ __forceinline__ float b2f(ushort u){
  return __uint_as_float((unsigned)u << 16);
}
__device__ __forceinline__ void unpk(unsigned u, float& a, float& b){
  a = __uint_as_float(u << 16);
  b = __uint_as_float(u & 0xffff0000u);
}

__device__ __forceinline__ void gload16(const void* g, void* l){
  __builtin_amdgcn_global_load_lds((const __attribute__((address_space(1))) void*)g,
                                   (__attribute__((address_space(3))) void*)l, 16, 0, 0);
}

__global__ void k_tables(float* __restrict__ cost, float* __restrict__ sint){
  int idx = blockIdx.x*256 + threadIdx.x;
  if (idx >= NTOK*16) return;
  int pos = idx >> 4, f = idx & 15;
  float inv = powf(10000.f, -(float)f/16.f);
  float ang = (float)pos * inv;
  cost[idx] = cosf(ang);
  sint[idx] = sinf(ang);
}

__global__ void k_copy(const float4* __restrict__ s, float4* __restrict__ d, int n){
  int i = blockIdx.x*256 + threadIdx.x;
  if (i < n) d[i] = s[i];
}

// fp32 (K,N) -> bf16 transposed (N,K)
__global__ __launch_bounds__(256) void k_wcvt(const float* __restrict__ W, ushort* __restrict__ Wt,
                                              int K, int N){
  __shared__ float t[32][33];
  int bx = blockIdx.x, by = blockIdx.y;
  int tx = threadIdx.x & 31, ty = threadIdx.x >> 5;
  #pragma unroll
  for (int r = ty; r < 32; r += 8) t[r][tx] = W[(size_t)(by*32+r)*N + bx*32 + tx];
  __syncthreads();
  #pragma unroll
  for (int r = ty; r < 32; r += 8) Wt[(size_t)(bx*32+r)*K + by*32 + tx] = f2b(t[tx][r]);
}

__global__ __launch_bounds__(256) void k_ln(const float* __restrict__ x, const float* __restrict__ g,
                     const float* __restrict__ b, ushort* __restrict__ y){
  int row = blockIdx.x, t = threadIdx.x;
  const float* xr = x + (size_t)row*C;
  float2 v = *(const float2*)(xr + 2*t);
  float s = v.x + v.y, ss = v.x*v.x + v.y*v.y;
  #pragma unroll
  for (int o = 32; o; o >>= 1){ s += __shfl_down(s, o); ss += __shfl_down(ss, o); }
  __shared__ float rs[4], rss[4];
  int wv = t >> 6, ln = t & 63;
  if (ln == 0){ rs[wv] = s; rss[wv] = ss; }
  __syncthreads();
  float S = rs[0]+rs[1]+rs[2]+rs[3], SS = rss[0]+rss[1]+rss[2]+rss[3];
  float mean = S * (1.f/C);
  float var  = SS * (1.f/C) - mean*mean;
  float rstd = rsqrtf(var + 1e-5f);
  float2 gg = *(const float2*)(g + 2*t);
  float2 bb = *(const float2*)(b + 2*t);
  ushort2 ov;
  ov.x = f2b((v.x - mean)*rstd*gg.x + bb.x);
  ov.y = f2b((v.y - mean)*rstd*gg.y + bb.y);
  *(ushort2*)(y + (size_t)row*C + 2*t) = ov;
}

// bf16 MFMA GEMM, m97 structure: out = ACT(A@B + bias) (+res)
// A: (M,K) bf16 row-major.  Bt: (N,K) bf16 row-major (i.e. B^T).
// grid (Nd/128, M/128), 256 threads (4 waves, 2x2 of 64x64).
// QKV==1: Nd=1536 logical; output de-interleaved into 3 contiguous (M,512)
// buffers at outb + bid*MROWS*C, with RoPE fused for local-head cols of q,k.
template<int ACT, int OBF, int QKV>
__global__ __launch_bounds__(256) void k_mgemm(const ushort* __restrict__ A, const ushort* __restrict__ Bt,
      const float* __restrict__ bias, const float* __restrict__ bias2, const float* __restrict__ bias3,
      const float* __restrict__ res, float* __restrict__ outf, ushort* __restrict__ outb,
      const float* __restrict__ cosT, const float* __restrict__ sinT, int Nd, int Kd){
  __shared__ ushort As[128*32];
  __shared__ ushort Bs[128*32];
  int tid = threadIdx.x;
  int lane = tid & 63, wave = tid >> 6;
  int wr = wave >> 1, wc = wave & 1;
  int row0 = blockIdx.y*128, col0 = blockIdx.x*128;
  f32x4 acc[4][4] = {};
  for (int k0 = 0; k0 < Kd; k0 += 32){
    __syncthreads();
    #pragma unroll
    for (int c = 0; c < 2; c++){
      int off = (wave*2 + c)*1024 + lane*16;       // byte offset in 8KB tile
      int r = off >> 6, ke = (off & 63) >> 1;      // row, k-element
      gload16(A  + (size_t)(row0 + r)*Kd + k0 + ke, (char*)As + (wave*2 + c)*1024);
      gload16(Bt + (size_t)(col0 + r)*Kd + k0 + ke, (char*)Bs + (wave*2 + c)*1024);
    }
    __syncthreads();
    bf16x8 af[4], bfr[4];
    #pragma unroll
    for (int m = 0; m < 4; m++)
      af[m] = *(const bf16x8*)((const char*)As + (wr*64 + m*16 + (lane&15))*64 + (lane>>4)*16);
    #pragma unroll
    for (int n = 0; n < 4; n++)
      bfr[n] = *(const bf16x8*)((const char*)Bs + (wc*64 + n*16 + (lane&15))*64 + (lane>>4)*16);
    #pragma unroll
    for (int m = 0; m < 4; m++)
      #pragma unroll
      for (int n = 0; n < 4; n++)
        acc[m][n] = __builtin_amdgcn_mfma_f32_16x16x32_bf16(af[m], bfr[n], acc[m][n], 0, 0, 0);
  }
  if (QKV){
    // de-interleave into q/k/v + fused RoPE on local-head cols of q,k
    #pragma unroll
    for (int m = 0; m < 4; m++){
      int rbase = row0 + wr*64 + m*16 + (lane>>4)*4;
      #pragma unroll
      for (int np = 0; np < 2; np++){
        int n0 = 2*np, n1 = n0 + 1;
        int ccol = col0 + wc*64 + n0*16 + (lane&15);   // ccol&31 == lane&15 (<16)
        int bid = ccol >> 9;
        int cl  = ccol & 511;
        const float* bp = (bid == 0) ? bias : (bid == 1) ? bias2 : bias3;
        float b0 = bp[cl], b1 = bp[cl+16];
        bool dorope = (bid < 2) && (cl >= 256);
        ushort* obase = outb + (size_t)bid*MROWS*C;
        int d = lane & 15;
        #pragma unroll
        for (int r = 0; r < 4; r++){
          int grow = rbase + r;
          float a  = acc[m][n0][r] + b0;
          float bb = acc[m][n1][r] + b1;
          if (dorope){
            int pos = grow & (NTOK-1);
            float cv = cosT[pos*16 + d], sv = sinT[pos*16 + d];
            float na = a*cv - bb*sv;
            float nb = bb*cv + a*sv;
            a = na; bb = nb;
          }
          obase[(size_t)grow*C + cl]      = f2b(a);
          obase[(size_t)grow*C + cl + 16] = f2b(bb);
        }
      }
    }
    return;
  }
  #pragma unroll
  for (int m = 0; m < 4; m++){
    int rbase = row0 + wr*64 + m*16 + (lane>>4)*4;
    #pragma unroll
    for (int n = 0; n < 4; n++){
      int ccol = col0 + wc*64 + n*16 + (lane&15);
      float bv = bias[ccol];
      #pragma unroll
      for (int r = 0; r < 4; r++){
        int grow = rbase + r;
        float vv = acc[m][n][r] + bv;
        if (ACT == 1) vv = 0.5f*vv*(1.f + erff(vv*0.7071067811865476f));
        if (res) vv += res[(size_t)grow*Nd + ccol];
        if (OBF) outb[(size_t)grow*Nd + ccol] = f2b(vv);
        else     outf[(size_t)grow*Nd + ccol] = vv;
      }
    }
  }
}

// Performer K pre-pass: per-row diag + per-(bh,chunk) max of dd. No atomics.
__global__ __launch_bounds__(256) void k_kpre(const ushort* __restrict__ k, const float* __restrict__ proj,
        float* __restrict__ diag, float* __restrict__ bmax){
  int bh = blockIdx.x >> 5, chunk = blockIdx.x & 31;
  int b = bh >> 3, h = bh & 7;
  __shared__ float pl[NBF][DH];
  int t = threadIdx.x;
  for (int idx = t; idx < NBF*DH; idx += 256) pl[idx>>5][idx&31] = proj[idx]*F_DN;
  __syncthreads();
  int i = chunk*256 + t;
  const ushort* kr = k + (size_t)(b*NTOK + i)*C + h*DH;
  ushort kt[32];
  *(uint4*)(kt)    = *(const uint4*)(kr);
  *(uint4*)(kt+8)  = *(const uint4*)(kr+8);
  *(uint4*)(kt+16) = *(const uint4*)(kr+16);
  *(uint4*)(kt+24) = *(const uint4*)(kr+24);
  float kv[DH];
  #pragma unroll
  for (int d = 0; d < DH; d++) kv[d] = b2f(kt[d]);
  float sq = 0.f;
  #pragma unroll
  for (int d = 0; d < DH; d++) sq += kv[d]*kv[d];
  diag[bh*NTOK + i] = 0.5f*F_DN*F_DN*sq;
  float mx = -1e30f;
  for (int m = 0; m < NBF; m++){
    float a = 0.f;
    #pragma unroll
    for (int d = 0; d < DH; d++) a += kv[d]*pl[m][d];
    mx = fmaxf(mx, a);
  }
  #pragma unroll
  for (int o = 32; o; o >>= 1) mx = fmaxf(mx, __shfl_down(mx, o));
  __shared__ float red[4];
  if ((t & 63) == 0) red[t>>6] = mx;
  __syncthreads();
  if (t == 0) bmax[bh*32 + chunk] = fmaxf(fmaxf(red[0],red[1]), fmaxf(red[2],red[3]));
}

__global__ void k_redmax(const float* __restrict__ bmax, float* __restrict__ stabf){
  int bh = blockIdx.x, t = threadIdx.x;
  float v = (t < 32) ? bmax[bh*32 + t] : -1e30f;
  #pragma unroll
  for (int o = 32; o; o >>= 1) v = fmaxf(v, __shfl_down(v, o));
  if (t == 0) stabf[bh] = v;
}

// Performer K pass 2: K/V staged once per chunk in LDS (fp32); thread t owns feature m=t.
__global__ __launch_bounds__(128) void k_ctx2(const ushort* __restrict__ k, const ushort* __restrict__ v,
        const float* __restrict__ proj, const float* __restrict__ diag, const float* __restrict__ stabf,
        float* __restrict__ ctxp, float* __restrict__ ksump){
  int bh = blockIdx.x >> 6, chunk = blockIdx.x & 63;
  int b = bh >> 3, h = bh & 7;
  __shared__ float pl[NBF][33];
  __shared__ float kl[128][DH];
  __shared__ float vl[128][DH];
  __shared__ float dg[128];
  int t = threadIdx.x;
  for (int idx = t; idx < NBF*DH; idx += 128){ int m = idx>>5, d = idx&31; pl[m][d] = proj[idx]*F_DN; }
  int i0 = chunk*128;
  for (int idx = t; idx < 128*4; idx += 128){
    int r = idx >> 2, f = idx & 3;
    size_t gofs = (size_t)(b*NTOK + i0 + r)*C + h*DH + f*8;
    uint4 kk = *(const uint4*)(k + gofs);
    uint4 vv = *(const uint4*)(v + gofs);
    float a, b2;
    unpk(kk.x,a,b2); kl[r][f*8+0]=a; kl[r][f*8+1]=b2;
    unpk(kk.y,a,b2); kl[r][f*8+2]=a; kl[r][f*8+3]=b2;
    unpk(kk.z,a,b2); kl[r][f*8+4]=a; kl[r][f*8+5]=b2;
    unpk(kk.w,a,b2); kl[r][f*8+6]=a; kl[r][f*8+7]=b2;
    unpk(vv.x,a,b2); vl[r][f*8+0]=a; vl[r][f*8+1]=b2;
    unpk(vv.y,a,b2); vl[r][f*8+2]=a; vl[r][f*8+3]=b2;
    unpk(vv.z,a,b2); vl[r][f*8+4]=a; vl[r][f*8+5]=b2;
    unpk(vv.w,a,b2); vl[r][f*8+6]=a; vl[r][f*8+7]=b2;
  }
  dg[t] = diag[bh*NTOK + i0 + t];
  __syncthreads();
  float st = stabf[bh];
  if (t < NBF){
    float acc[DH] = {};
    float ks = 0.f;
    for (int r = 0; r < 128; r++){
      float dd = 0.f;
      #pragma unroll
      for (int d = 0; d < DH; d++) dd += kl[r][d]*pl[t][d];
      float kp = F_RNORM*(expf(dd - dg[r] - st) + 1e-4f);
      ks += kp;
      #pragma unroll
      for (int d = 0; d < DH; d++) acc[d] += kp*vl[r][d];
    }
    size_t base = (((size_t)bh*64 + chunk)*NBF + t)*DH;
    #pragma unroll
    for (int d = 0; d < DH; d++) ctxp[base + d] = acc[d];
    ksump[((size_t)bh*64 + chunk)*NBF + t] = ks;
  }
}

__global__ void k_ctxred(const float* __restrict__ ctxp, const float* __restrict__ ksump,
                         float* __restrict__ ctx, float* __restrict__ ksum){
  int bh = blockIdx.x / NBF, m = blockIdx.x % NBF;
  int t = threadIdx.x;
  if (t < DH){
    float s = 0.f;
    for (int c = 0; c < 64; c++) s += ctxp[(((size_t)bh*64 + c)*NBF + m)*DH + t];
    ctx[((size_t)bh*NBF + m)*DH + t] = s;
  } else if (t == DH){
    float s = 0.f;
    for (int c = 0; c < 64; c++) s += ksump[((size_t)bh*64 + c)*NBF + m];
    ksum[bh*NBF + m] = s;
  }
}

// Performer Q side v2: one block per (bh, 128-row chunk); thread t owns row i0+t.
__global__ __launch_bounds__(128) void k_qattn2(const ushort* __restrict__ q, const float* __restrict__ proj,
        const float* __restrict__ ctx, const float* __restrict__ ksum, ushort* __restrict__ o){
  int bh = blockIdx.x >> 6, chunk = blockIdx.x & 63;
  int b = bh >> 3, h = bh & 7;
  __shared__ float pl[NBF][DH];
  __shared__ float cl[NBF][DH];
  __shared__ float ksl[NBF];
  __shared__ float ql[128][33];
  int t = threadIdx.x;
  for (int idx = t; idx < NBF*DH; idx += 128){
    pl[idx>>5][idx&31] = proj[idx]*F_DN;
    cl[idx>>5][idx&31] = ctx[(size_t)bh*NBF*DH + idx];
  }
  if (t < NBF) ksl[t] = ksum[bh*NBF + t];
  int i0 = chunk*128;
  for (int idx = t; idx < 128*4; idx += 128){
    int r = idx >> 2, f = idx & 3;
    uint4 qq = *(const uint4*)(q + (size_t)(b*NTOK + i0 + r)*C + h*DH + f*8);
    float a, b2;
    unpk(qq.x,a,b2); ql[r][f*8+0]=a; ql[r][f*8+1]=b2;
    unpk(qq.y,a,b2); ql[r][f*8+2]=a; ql[r][f*8+3]=b2;
    unpk(qq.z,a,b2); ql[r][f*8+4]=a; ql[r][f*8+5]=b2;
    unpk(qq.w,a,b2); ql[r][f*8+6]=a; ql[r][f*8+7]=b2;
  }
  __syncthreads();
  float qv[DH];
  #pragma unroll
  for (int d = 0; d < DH; d++) qv[d] = ql[t][d];
  float sq = 0.f;
  #pragma unroll
  for (int d = 0; d < DH; d++) sq += qv[d]*qv[d];
  float diagv = 0.5f*F_DN*F_DN*sq;
  float mx = -1e30f;
  for (int m = 0; m < NBF; m++){
    float dd = 0.f;
    #pragma unroll
    for (int d = 0; d < DH; d++) dd += qv[d]*pl[m][d];
    mx = fmaxf(mx, dd);
  }
  float og[DH] = {};
  float Dv = 0.f;
  for (int m = 0; m < NBF; m++){
    float dd = 0.f;
    #pragma unroll
    for (int d = 0; d < DH; d++) dd += qv[d]*pl[m][d];
    float qp = F_RNORM*(expf(dd - diagv - mx) + 1e-4f);
    Dv += qp*ksl[m];
    #pragma unroll
    for (int d = 0; d < DH; d++) og[d] += qp*cl[m][d];
  }
  float Dinv = 1.f/Dv;
  ushort* orow = o + (size_t)(b*NTOK + i0 + t)*C + h*DH;
  #pragma unroll
  for (int d = 0; d < DH; d += 2){
    unsigned pk = (unsigned)f2b(og[d]*Dinv) | ((unsigned)f2b(og[d+1]*Dinv) << 16);
    *(unsigned*)(orow + d) = pk;
  }
}

// Local windowed attention via MFMA. One block per (b, head, window); 4 waves x 16 q-rows.
// S^T = K·Q^T (A=K rows, B=Q rows); softmax in-register (no stab: scores O(1));
// P -> LDS bf16; O^T = V^T·P^T (A=V^T rows, B=P rows). All LDS reads natural b128.
__global__ __launch_bounds__(256) void k_local2(const ushort* __restrict__ q, const ushort* __restrict__ k,
        const ushort* __restrict__ v, ushort* __restrict__ o){
  int blk = blockIdx.x;
  int w = blk & (NW-1);
  int rem = blk >> 7;
  int hl = rem & 7, b = rem >> 3;
  int hd = GH + hl;
  __shared__ __align__(16) ushort Ks[192*32];      // [key][d]        12.0KB
  __shared__ __align__(16) ushort Vt[32*200];      // [d][key] pad    12.5KB
  __shared__ __align__(16) ushort Ps[4*16*200];    // per-wave [q][key] pad 25KB
  int tid = threadIdx.x;
  int lane = tid & 63, wave = tid >> 6;
  int c = lane & 15, g = lane >> 4;

  const ushort* kbase = k + (size_t)b*NTOK*C + hd*DH;
  const ushort* vbase = v + (size_t)b*NTOK*C + hd*DH;
  // stage K linear [192][32] via global_load_lds (768 x 16B chunks)
  #pragma unroll
  for (int s = 0; s < 3; s++){
    int ch = tid + s*256;
    int row = ch >> 2, part = ch & 3;
    int kp = min(max((w-1)*WIN + row, 0), NTOK-1);
    gload16(kbase + (size_t)kp*C + part*8, (char*)Ks + (s*256 + wave*64)*16);
  }
  // stage V transposed [32][200]
  #pragma unroll
  for (int s = 0; s < 3; s++){
    int ch = tid + s*256;
    int row = ch >> 2, part = ch & 3;
    int kp = min(max((w-1)*WIN + row, 0), NTOK-1);
    uint4 vv = *(const uint4*)(vbase + (size_t)kp*C + part*8);
    const ushort* vp = (const ushort*)&vv;
    #pragma unroll
    for (int j = 0; j < 8; j++) Vt[(part*8+j)*200 + row] = vp[j];
  }
  // Q B-frag: lane holds Q[c][8g..8g+7] of this wave's 16 rows
  int qrow = w*WIN + wave*16 + c;
  bf16x8 qf = *(const bf16x8*)(q + ((size_t)b*NTOK + qrow)*C + hd*DH + g*8);
  asm volatile("s_waitcnt vmcnt(0)" ::: "memory");
  __syncthreads();

  f32x4 zz = {0.f, 0.f, 0.f, 0.f};
  f32x4 st[12];
  #pragma unroll
  for (int t = 0; t < 12; t++){
    bf16x8 af = *(const bf16x8*)(Ks + (16*t + c)*32 + g*8);
    st[t] = __builtin_amdgcn_mfma_f32_16x16x32_bf16(af, qf, zz, 0, 0, 0);
  }
  int t0 = (w == 0) ? 4 : 0;
  int t1 = (w == NW-1) ? 8 : 12;
  float lsum = 0.f;
  ushort* pw = Ps + wave*3200 + c*200;
  #pragma unroll
  for (int t = 0; t < 12; t++){
    bool valid = (t >= t0) && (t < t1);
    float p0 = valid ? __expf(st[t][0]*F_LSCALE) : 0.f;
    float p1 = valid ? __expf(st[t][1]*F_LSCALE) : 0.f;
    float p2 = valid ? __expf(st[t][2]*F_LSCALE) : 0.f;
    float p3 = valid ? __expf(st[t][3]*F_LSCALE) : 0.f;
    lsum += (p0+p1)+(p2+p3);
    uint2 pd;
    pd.x = (unsigned)f2b(p0) | ((unsigned)f2b(p1) << 16);
    pd.y = (unsigned)f2b(p2) | ((unsigned)f2b(p3) << 16);
    *(uint2*)(pw + 16*t + 4*g) = pd;
  }
  lsum += __shfl_xor(lsum, 16);
  lsum += __shfl_xor(lsum, 32);

  f32x4 oc0 = zz, oc1 = zz;
  #pragma unroll
  for (int kb = 0; kb < 6; kb++){
    bf16x8 pf = *(const bf16x8*)(pw + kb*32 + g*8);
    bf16x8 v0 = *(const bf16x8*)(Vt + c*200 + kb*32 + g*8);
    bf16x8 v1 = *(const bf16x8*)(Vt + (16 + c)*200 + kb*32 + g*8);
    oc0 = __builtin_amdgcn_mfma_f32_16x16x32_bf16(v0, pf, oc0, 0, 0, 0);
    oc1 = __builtin_amdgcn_mfma_f32_16x16x32_bf16(v1, pf, oc1, 0, 0, 0);
  }
  float inv = 1.f/lsum;
  ushort* orow = o + ((size_t)b*NTOK + qrow)*C + hd*DH;
  uint2 w0, w1;
  w0.x = (unsigned)f2b(oc0[0]*inv) | ((unsigned)f2b(oc0[1]*inv) << 16);
  w0.y = (unsigned)f2b(oc0[2]*inv) | ((unsigned)f2b(oc0[3]*inv) << 16);
  w1.x = (unsigned)f2b(oc1[0]*inv) | ((unsigned)f2b(oc1[1]*inv) << 16);
  w1.y = (unsigned)f2b(oc1[2]*inv) | ((unsigned)f2b(oc1[3]*inv) << 16);
  *(uint2*)(orow + 4*g)      = w0;
  *(uint2*)(orow + 16 + 4*g) = w1;
}

} // namespace

extern "C" void kernel_launch(void* const* d_in, const int* in_sizes, int n_in,
                              void* d_out, int out_size, void* d_ws, size_t ws_size,
                              hipStream_t stream){
  (void)in_sizes; (void)n_in; (void)out_size; (void)ws_size;
  const float* x     = (const float*)d_in[0];
  const float* ln1_g = (const float*)d_in[1];
  const float* ln1_b = (const float*)d_in[2];
  const float* Wq    = (const float*)d_in[3];
  const float* bq    = (const float*)d_in[4];
  const float* Wk    = (const float*)d_in[5];
  const float* bk    = (const float*)d_in[6];
  const float* Wv    = (const float*)d_in[7];
  const float* bv    = (const float*)d_in[8];
  const float* Wo    = (const float*)d_in[9];
  const float* bo    = (const float*)d_in[10];
  const float* proj  = (const float*)d_in[11];
  const float* ln2_g = (const float*)d_in[12];
  const float* ln2_b = (const float*)d_in[13];
  const float* W1    = (const float*)d_in[14];
  const float* b1    = (const float*)d_in[15];
  const float* W2    = (const float*)d_in[16];
  const float* b2    = (const float*)d_in[17];

  float* h = (float*)d_out;
  const size_t MC = (size_t)MROWS*C;
  char* w = (char*)d_ws;
  auto alloc = [&](size_t bytes)->char*{ char* p = w; w += (bytes + 255) & ~(size_t)255; return p; };

  ushort* y16  = (ushort*)alloc(MC*2);
  ushort* qb16 = (ushort*)alloc(MC*2);   // q,k,v contiguous: QKV-fused epilogue indexes bid*MC
  ushort* kb16 = (ushort*)alloc(MC*2);
  ushort* vb16 = (ushort*)alloc(MC*2);
  ushort* o16  = (ushort*)alloc(MC*2);
  ushort* wt   = (ushort*)alloc((size_t)2097152*2);   // per-layer transposed bf16 weights
  float*  cost = (float*) alloc((size_t)NTOK*16*4);
  float*  sint = (float*) alloc((size_t)NTOK*16*4);
  float*  diag = (float*) alloc((size_t)16*NTOK*4);
  float*  bmax = (float*) alloc(16*32*4);
  float*  stabf= (float*) alloc(16*4);
  float*  ctxb = (float*) alloc((size_t)16*NBF*DH*4);
  float*  ksum = (float*) alloc((size_t)16*NBF*4);

  ushort* mid16 = qb16;                    // FFN mid (M*FF bf16 = 32MB) aliases qb16+kb16 (dead)
  float*  ctxp  = (float*)o16;             // ctx partials (14.4MB) alias o16 (written later)
  float*  ksump = ctxp + (size_t)16*64*NBF*DH;

  ushort* wtq = wt;                        // wtq/wtk/wtv contiguous -> fused (1536,512) B^T
  ushort* wtk = wt +  262144;
  ushort* wtv = wt +  524288;
  ushort* wto = wt +  786432;
  ushort* wt1 = wt + 1048576;
  ushort* wt2 = wt + 1572864;

  k_tables<<<(NTOK*16 + 255)/256, 256, 0, stream>>>(cost, sint);
  k_copy<<<(int)((MC/4 + 255)/256), 256, 0, stream>>>((const float4*)x, (float4*)h, (int)(MC/4));

  dim3 blk(256);
  dim3 g512(4, 128);    // N=512
  dim3 gqkv(12, 128);   // N=1536 fused
  dim3 gff(8, 128);     // N=1024

  for (int l = 0; l < 2; l++){
    const float* pj = proj + (size_t)l*NBF*DH;
    k_wcvt<<<dim3(16,16), blk, 0, stream>>>(Wq + (size_t)l*C*C,  wtq, C, C);
    k_wcvt<<<dim3(16,16), blk, 0, stream>>>(Wk + (size_t)l*C*C,  wtk, C, C);
    k_wcvt<<<dim3(16,16), blk, 0, stream>>>(Wv + (size_t)l*C*C,  wtv, C, C);
    k_wcvt<<<dim3(16,16), blk, 0, stream>>>(Wo + (size_t)l*C*C,  wto, C, C);
    k_wcvt<<<dim3(32,16), blk, 0, stream>>>(W1 + (size_t)l*C*FF, wt1, C, FF);
    k_wcvt<<<dim3(16,32), blk, 0, stream>>>(W2 + (size_t)l*FF*C, wt2, FF, C);

    k_ln<<<MROWS, 256, 0, stream>>>(h, ln1_g + l*C, ln1_b + l*C, y16);
    k_mgemm<0,1,1><<<gqkv, blk, 0, stream>>>(y16, wtq, bq + l*C, bk + l*C, bv + l*C,
                                             nullptr, nullptr, qb16, cost, sint, 1536, C);
    k_kpre<<<16*32, 256, 0, stream>>>(kb16, pj, diag, bmax);
    k_redmax<<<16, 64, 0, stream>>>(bmax, stabf);
    k_ctx2<<<16*64, 128, 0, stream>>>(kb16, vb16, pj, diag, stabf, ctxp, ksump);
    k_ctxred<<<16*NBF, 64, 0, stream>>>(ctxp, ksump, ctxb, ksum);
    k_qattn2<<<16*64, 128, 0, stream>>>(qb16, pj, ctxb, ksum, o16);
    k_local2<<<BATCH*8*NW, 256, 0, stream>>>(qb16, kb16, vb16, o16);
    k_mgemm<0,0,0><<<g512, blk, 0, stream>>>(o16, wto, bo + l*C, nullptr, nullptr, h, h, nullptr,
                                             nullptr, nullptr, C, C);
    k_ln<<<MROWS, 256, 0, stream>>>(h, ln2_g + l*C, ln2_b + l*C, y16);
    k_mgemm<1,1,0><<<gff, blk, 0, stream>>>(y16, wt1, b1 + l*FF, nullptr, nullptr, nullptr,
                                            nullptr, mid16, nullptr, nullptr, FF, C);
    k_mgemm<0,0,0><<<g512, blk, 0, stream>>>(mid16, wt2, b2 + l*C, nullptr, nullptr, h, h, nullptr,
                                             nullptr, nullptr, C, FF);
  }
}

// Round 6
// 813.047 us; speedup vs baseline: 8.9255x; 1.1981x over previous
//
#include <hip/hip_runtime.h>
#include <math.h>

namespace {

constexpr int BATCH = 2;
constexpr int NTOK  = 8192;    // tokens per batch (T*H*W)
constexpr int MROWS = 16384;   // BATCH*NTOK
constexpr int C     = 512;
constexpr int GH    = 8;
constexpr int DH    = 32;
constexpr int WIN   = 64;
constexpr int NW    = 128;     // NTOK/WIN
constexpr int FF    = 1024;
constexpr int NBF   = 110;     // int(32*ln(32))
constexpr int NBFP  = 128;     // padded feature count (MFMA tiles)

constexpr float F_DN     = 0.42044820762685725f;   // 32^-0.25
constexpr float F_RNORM  = 0.09534625892455924f;   // 110^-0.5
constexpr float F_LSCALE = 0.17677669529663687f;   // 32^-0.5

typedef __attribute__((ext_vector_type(8))) short bf16x8;
typedef __attribute__((ext_vector_type(4))) float f32x4;

__device__ __forceinline__ ushort f2b(float f){
  unsigned u = __float_as_uint(f);
  unsigned r = u + 0x7FFFu + ((u >> 16) & 1u);
  return (ushort)(r >> 16);
}
__device__ __forceinline__ float b2f(ushort u){
  return __uint_as_float((unsigned)u << 16);
}
__device__ __forceinline__ void unpk(unsigned u, float& a, float& b){
  a = __uint_as_float(u << 16);
  b = __uint_as_float(u & 0xffff0000u);
}

__device__ __forceinline__ void gload16(const void* g, void* l){
  __builtin_amdgcn_global_load_lds((const __attribute__((address_space(1))) void*)g,
                                   (__attribute__((address_space(3))) void*)l, 16, 0, 0);
}

__global__ void k_tables(float* __restrict__ cost, float* __restrict__ sint){
  int idx = blockIdx.x*256 + threadIdx.x;
  if (idx >= NTOK*16) return;
  int pos = idx >> 4, f = idx & 15;
  float inv = powf(10000.f, -(float)f/16.f);
  float ang = (float)pos * inv;
  cost[idx] = cosf(ang);
  sint[idx] = sinf(ang);
}

__global__ void k_copy(const float4* __restrict__ s, float4* __restrict__ d, int n){
  int i = blockIdx.x*256 + threadIdx.x;
  if (i < n) d[i] = s[i];
}

// fp32 (K,N) -> bf16 transposed (N,K)
__global__ __launch_bounds__(256) void k_wcvt(const float* __restrict__ W, ushort* __restrict__ Wt,
                                              int K, int N){
  __shared__ float t[32][33];
  int bx = blockIdx.x, by = blockIdx.y;
  int tx = threadIdx.x & 31, ty = threadIdx.x >> 5;
  #pragma unroll
  for (int r = ty; r < 32; r += 8) t[r][tx] = W[(size_t)(by*32+r)*N + bx*32 + tx];
  __syncthreads();
  #pragma unroll
  for (int r = ty; r < 32; r += 8) Wt[(size_t)(bx*32+r)*K + by*32 + tx] = f2b(t[tx][r]);
}

__global__ __launch_bounds__(256) void k_ln(const float* __restrict__ x, const float* __restrict__ g,
                     const float* __restrict__ b, ushort* __restrict__ y){
  int row = blockIdx.x, t = threadIdx.x;
  const float* xr = x + (size_t)row*C;
  float2 v = *(const float2*)(xr + 2*t);
  float s = v.x + v.y, ss = v.x*v.x + v.y*v.y;
  #pragma unroll
  for (int o = 32; o; o >>= 1){ s += __shfl_down(s, o); ss += __shfl_down(ss, o); }
  __shared__ float rs[4], rss[4];
  int wv = t >> 6, ln = t & 63;
  if (ln == 0){ rs[wv] = s; rss[wv] = ss; }
  __syncthreads();
  float S = rs[0]+rs[1]+rs[2]+rs[3], SS = rss[0]+rss[1]+rss[2]+rss[3];
  float mean = S * (1.f/C);
  float var  = SS * (1.f/C) - mean*mean;
  float rstd = rsqrtf(var + 1e-5f);
  float2 gg = *(const float2*)(g + 2*t);
  float2 bb = *(const float2*)(b + 2*t);
  ushort2 ov;
  ov.x = f2b((v.x - mean)*rstd*gg.x + bb.x);
  ov.y = f2b((v.y - mean)*rstd*gg.y + bb.y);
  *(ushort2*)(y + (size_t)row*C + 2*t) = ov;
}

// bf16 MFMA GEMM, m97 structure: out = ACT(A@B + bias) (+res)
// A: (M,K) bf16 row-major.  Bt: (N,K) bf16 row-major (i.e. B^T).
// grid (Nd/128, M/128), 256 threads (4 waves, 2x2 of 64x64).
// QKV==1: Nd=1536 logical; output de-interleaved into 3 contiguous (M,512)
// buffers at outb + bid*MROWS*C, with RoPE fused for local-head cols of q,k.
template<int ACT, int OBF, int QKV>
__global__ __launch_bounds__(256) void k_mgemm(const ushort* __restrict__ A, const ushort* __restrict__ Bt,
      const float* __restrict__ bias, const float* __restrict__ bias2, const float* __restrict__ bias3,
      const float* __restrict__ res, float* __restrict__ outf, ushort* __restrict__ outb,
      const float* __restrict__ cosT, const float* __restrict__ sinT, int Nd, int Kd){
  __shared__ ushort As[128*32];
  __shared__ ushort Bs[128*32];
  int tid = threadIdx.x;
  int lane = tid & 63, wave = tid >> 6;
  int wr = wave >> 1, wc = wave & 1;
  int row0 = blockIdx.y*128, col0 = blockIdx.x*128;
  f32x4 acc[4][4] = {};
  for (int k0 = 0; k0 < Kd; k0 += 32){
    __syncthreads();
    #pragma unroll
    for (int c = 0; c < 2; c++){
      int off = (wave*2 + c)*1024 + lane*16;       // byte offset in 8KB tile
      int r = off >> 6, ke = (off & 63) >> 1;      // row, k-element
      gload16(A  + (size_t)(row0 + r)*Kd + k0 + ke, (char*)As + (wave*2 + c)*1024);
      gload16(Bt + (size_t)(col0 + r)*Kd + k0 + ke, (char*)Bs + (wave*2 + c)*1024);
    }
    __syncthreads();
    bf16x8 af[4], bfr[4];
    #pragma unroll
    for (int m = 0; m < 4; m++)
      af[m] = *(const bf16x8*)((const char*)As + (wr*64 + m*16 + (lane&15))*64 + (lane>>4)*16);
    #pragma unroll
    for (int n = 0; n < 4; n++)
      bfr[n] = *(const bf16x8*)((const char*)Bs + (wc*64 + n*16 + (lane&15))*64 + (lane>>4)*16);
    #pragma unroll
    for (int m = 0; m < 4; m++)
      #pragma unroll
      for (int n = 0; n < 4; n++)
        acc[m][n] = __builtin_amdgcn_mfma_f32_16x16x32_bf16(af[m], bfr[n], acc[m][n], 0, 0, 0);
  }
  if (QKV){
    // de-interleave into q/k/v + fused RoPE on local-head cols of q,k
    #pragma unroll
    for (int m = 0; m < 4; m++){
      int rbase = row0 + wr*64 + m*16 + (lane>>4)*4;
      #pragma unroll
      for (int np = 0; np < 2; np++){
        int n0 = 2*np, n1 = n0 + 1;
        int ccol = col0 + wc*64 + n0*16 + (lane&15);   // ccol&31 == lane&15 (<16)
        int bid = ccol >> 9;
        int cl  = ccol & 511;
        const float* bp = (bid == 0) ? bias : (bid == 1) ? bias2 : bias3;
        float b0 = bp[cl], b1 = bp[cl+16];
        bool dorope = (bid < 2) && (cl >= 256);
        ushort* obase = outb + (size_t)bid*MROWS*C;
        int d = lane & 15;
        #pragma unroll
        for (int r = 0; r < 4; r++){
          int grow = rbase + r;
          float a  = acc[m][n0][r] + b0;
          float bb = acc[m][n1][r] + b1;
          if (dorope){
            int pos = grow & (NTOK-1);
            float cv = cosT[pos*16 + d], sv = sinT[pos*16 + d];
            float na = a*cv - bb*sv;
            float nb = bb*cv + a*sv;
            a = na; bb = nb;
          }
          obase[(size_t)grow*C + cl]      = f2b(a);
          obase[(size_t)grow*C + cl + 16] = f2b(bb);
        }
      }
    }
    return;
  }
  #pragma unroll
  for (int m = 0; m < 4; m++){
    int rbase = row0 + wr*64 + m*16 + (lane>>4)*4;
    #pragma unroll
    for (int n = 0; n < 4; n++){
      int ccol = col0 + wc*64 + n*16 + (lane&15);
      float bv = bias[ccol];
      #pragma unroll
      for (int r = 0; r < 4; r++){
        int grow = rbase + r;
        float vv = acc[m][n][r] + bv;
        if (ACT == 1) vv = 0.5f*vv*(1.f + erff(vv*0.7071067811865476f));
        if (res) vv += res[(size_t)grow*Nd + ccol];
        if (OBF) outb[(size_t)grow*Nd + ccol] = f2b(vv);
        else     outf[(size_t)grow*Nd + ccol] = vv;
      }
    }
  }
}

// Performer K pre-pass: per-row diag + per-(bh,chunk) max of dd. No atomics.
__global__ __launch_bounds__(256) void k_kpre(const ushort* __restrict__ k, const float* __restrict__ proj,
        float* __restrict__ diag, float* __restrict__ bmax){
  int bh = blockIdx.x >> 5, chunk = blockIdx.x & 31;
  int b = bh >> 3, h = bh & 7;
  __shared__ float pl[NBF][DH];
  int t = threadIdx.x;
  for (int idx = t; idx < NBF*DH; idx += 256) pl[idx>>5][idx&31] = proj[idx]*F_DN;
  __syncthreads();
  int i = chunk*256 + t;
  const ushort* kr = k + (size_t)(b*NTOK + i)*C + h*DH;
  ushort kt[32];
  *(uint4*)(kt)    = *(const uint4*)(kr);
  *(uint4*)(kt+8)  = *(const uint4*)(kr+8);
  *(uint4*)(kt+16) = *(const uint4*)(kr+16);
  *(uint4*)(kt+24) = *(const uint4*)(kr+24);
  float kv[DH];
  #pragma unroll
  for (int d = 0; d < DH; d++) kv[d] = b2f(kt[d]);
  float sq = 0.f;
  #pragma unroll
  for (int d = 0; d < DH; d++) sq += kv[d]*kv[d];
  diag[bh*NTOK + i] = 0.5f*F_DN*F_DN*sq;
  float mx = -1e30f;
  for (int m = 0; m < NBF; m++){
    float a = 0.f;
    #pragma unroll
    for (int d = 0; d < DH; d++) a += kv[d]*pl[m][d];
    mx = fmaxf(mx, a);
  }
  #pragma unroll
  for (int o = 32; o; o >>= 1) mx = fmaxf(mx, __shfl_down(mx, o));
  __shared__ float red[4];
  if ((t & 63) == 0) red[t>>6] = mx;
  __syncthreads();
  if (t == 0) bmax[bh*32 + chunk] = fmaxf(fmaxf(red[0],red[1]), fmaxf(red[2],red[3]));
}

__global__ void k_redmax(const float* __restrict__ bmax, float* __restrict__ stabf){
  int bh = blockIdx.x, t = threadIdx.x;
  float v = (t < 32) ? bmax[bh*32 + t] : -1e30f;
  #pragma unroll
  for (int o = 32; o; o >>= 1) v = fmaxf(v, __shfl_down(v, o));
  if (t == 0) stabf[bh] = v;
}

// Performer K pass 2: K/V staged once per chunk in LDS (fp32); thread t owns feature m=t.
__global__ __launch_bounds__(128) void k_ctx2(const ushort* __restrict__ k, const ushort* __restrict__ v,
        const float* __restrict__ proj, const float* __restrict__ diag, const float* __restrict__ stabf,
        float* __restrict__ ctxp, float* __restrict__ ksump){
  int bh = blockIdx.x >> 6, chunk = blockIdx.x & 63;
  int b = bh >> 3, h = bh & 7;
  __shared__ float pl[NBF][33];
  __shared__ float kl[128][DH];
  __shared__ float vl[128][DH];
  __shared__ float dg[128];
  int t = threadIdx.x;
  for (int idx = t; idx < NBF*DH; idx += 128){ int m = idx>>5, d = idx&31; pl[m][d] = proj[idx]*F_DN; }
  int i0 = chunk*128;
  for (int idx = t; idx < 128*4; idx += 128){
    int r = idx >> 2, f = idx & 3;
    size_t gofs = (size_t)(b*NTOK + i0 + r)*C + h*DH + f*8;
    uint4 kk = *(const uint4*)(k + gofs);
    uint4 vv = *(const uint4*)(v + gofs);
    float a, b2;
    unpk(kk.x,a,b2); kl[r][f*8+0]=a; kl[r][f*8+1]=b2;
    unpk(kk.y,a,b2); kl[r][f*8+2]=a; kl[r][f*8+3]=b2;
    unpk(kk.z,a,b2); kl[r][f*8+4]=a; kl[r][f*8+5]=b2;
    unpk(kk.w,a,b2); kl[r][f*8+6]=a; kl[r][f*8+7]=b2;
    unpk(vv.x,a,b2); vl[r][f*8+0]=a; vl[r][f*8+1]=b2;
    unpk(vv.y,a,b2); vl[r][f*8+2]=a; vl[r][f*8+3]=b2;
    unpk(vv.z,a,b2); vl[r][f*8+4]=a; vl[r][f*8+5]=b2;
    unpk(vv.w,a,b2); vl[r][f*8+6]=a; vl[r][f*8+7]=b2;
  }
  dg[t] = diag[bh*NTOK + i0 + t];
  __syncthreads();
  float st = stabf[bh];
  if (t < NBF){
    float acc[DH] = {};
    float ks = 0.f;
    for (int r = 0; r < 128; r++){
      float dd = 0.f;
      #pragma unroll
      for (int d = 0; d < DH; d++) dd += kl[r][d]*pl[t][d];
      float kp = F_RNORM*(expf(dd - dg[r] - st) + 1e-4f);
      ks += kp;
      #pragma unroll
      for (int d = 0; d < DH; d++) acc[d] += kp*vl[r][d];
    }
    size_t base = (((size_t)bh*64 + chunk)*NBF + t)*DH;
    #pragma unroll
    for (int d = 0; d < DH; d++) ctxp[base + d] = acc[d];
    ksump[((size_t)bh*64 + chunk)*NBF + t] = ks;
  }
}

__global__ void k_ctxred(const float* __restrict__ ctxp, const float* __restrict__ ksump,
                         float* __restrict__ ctx, float* __restrict__ ksum){
  int bh = blockIdx.x / NBF, m = blockIdx.x % NBF;
  int t = threadIdx.x;
  if (t < DH){
    float s = 0.f;
    for (int c = 0; c < 64; c++) s += ctxp[(((size_t)bh*64 + c)*NBF + m)*DH + t];
    ctx[((size_t)bh*NBF + m)*DH + t] = s;
  } else if (t == DH){
    float s = 0.f;
    for (int c = 0; c < 64; c++) s += ksump[((size_t)bh*64 + c)*NBF + m];
    ksum[bh*NBF + m] = s;
  }
}

// Performer Q side v3 (MFMA). One block per (bh, 64 q-rows); 4 waves, wave w owns q-rows 16w..16w+15.
// S^T[feat,qrow] = proj_pad . Q^T  (8 MFMA/wave, K=32)
// row-max/Dv: 4-lane shfl_xor reduce in C layout; qp=exp(..)+1e-4 (padded feats -> 0)
// P[qrow][feat] bf16 in LDS; og = P . ctxT^T (8 MFMA/wave, K=128); scale by 1/Dv.
__global__ __launch_bounds__(256) void k_qattn3(const ushort* __restrict__ q, const float* __restrict__ proj,
        const float* __restrict__ ctx, const float* __restrict__ ksum, ushort* __restrict__ o){
  int bh = blockIdx.x >> 7, chunk = blockIdx.x & 127;
  int b = bh >> 3, h = bh & 7;
  __shared__ __align__(16) ushort pl[NBFP*40];    // proj bf16 [feat][40 pad]   10.0KB
  __shared__ __align__(16) ushort ql[64*40];      // Q [qrow][40 pad]            5.0KB
  __shared__ __align__(16) ushort ctl[32*136];    // ctx^T [d][136 pad]          8.5KB
  __shared__ __align__(16) ushort Ps[64*136];     // P [qrow][136 pad]          17.0KB
  __shared__ float ksl[NBFP];
  __shared__ float dgl[64];
  __shared__ float dvl[64];
  int tid = threadIdx.x;
  int lane = tid & 63, wave = tid >> 6;
  int c = lane & 15, g = lane >> 4;
  int i0 = chunk*64;

  // stage proj -> bf16 (pad feats >=NBF to 0)
  for (int idx = tid; idx < NBFP*32; idx += 256){
    int f = idx >> 5, d = idx & 31;
    pl[f*40 + d] = (f < NBF) ? f2b(proj[f*32 + d]*F_DN) : (ushort)0;
  }
  // stage Q rows + diag partials (4 threads per row, shfl-reduce within)
  {
    int row = tid >> 2, part = tid & 3;
    uint4 qq = *(const uint4*)(q + (size_t)(b*NTOK + i0 + row)*C + h*DH + part*8);
    *(uint4*)(ql + row*40 + part*8) = qq;
    const ushort* qp_ = (const ushort*)&qq;
    float sq = 0.f;
    #pragma unroll
    for (int j = 0; j < 8; j++){ float vv = b2f(qp_[j]); sq += vv*vv; }
    sq += __shfl_xor(sq, 1);
    sq += __shfl_xor(sq, 2);
    if (part == 0) dgl[row] = 0.5f*F_DN*F_DN*sq;
  }
  // stage ctx^T bf16 (pad feats -> 0)
  for (int idx = tid; idx < 32*NBFP; idx += 256){
    int d = idx >> 7, f = idx & 127;
    float vv = (f < NBF) ? ctx[((size_t)bh*NBF + f)*DH + d] : 0.f;
    ctl[d*136 + f] = f2b(vv);
  }
  if (tid < NBFP) ksl[tid] = (tid < NBF) ? ksum[bh*NBF + tid] : 0.f;
  __syncthreads();

  // QK: S^T frags, M=feat tiles (8), N=this wave's qrow tile
  f32x4 zz = {0.f, 0.f, 0.f, 0.f};
  bf16x8 qf = *(const bf16x8*)(ql + (wave*16 + c)*40 + g*8);
  f32x4 st[8];
  #pragma unroll
  for (int mt = 0; mt < 8; mt++){
    bf16x8 af = *(const bf16x8*)(pl + (mt*16 + c)*40 + g*8);
    st[mt] = __builtin_amdgcn_mfma_f32_16x16x32_bf16(af, qf, zz, 0, 0, 0);
  }
  // row max over valid feats (feat = mt*16 + g*4 + r), reduce across 4-lane group
  float mx = -1e30f;
  #pragma unroll
  for (int mt = 0; mt < 8; mt++)
    #pragma unroll
    for (int r = 0; r < 4; r++){
      int feat = mt*16 + g*4 + r;
      if (feat < NBF) mx = fmaxf(mx, st[mt][r]);
    }
  mx = fmaxf(mx, __shfl_xor(mx, 16));
  mx = fmaxf(mx, __shfl_xor(mx, 32));
  // qp, Dv, P write
  float diagv = dgl[wave*16 + c];
  float dv = 0.f;
  #pragma unroll
  for (int mt = 0; mt < 8; mt++){
    ushort pb[4];
    #pragma unroll
    for (int r = 0; r < 4; r++){
      int feat = mt*16 + g*4 + r;
      float qp = 0.f;
      if (feat < NBF) qp = F_RNORM*(__expf(st[mt][r] - diagv - mx) + 1e-4f);
      ushort qb = f2b(qp);
      pb[r] = qb;
      dv += b2f(qb)*ksl[feat];
    }
    uint2 pd;
    pd.x = (unsigned)pb[0] | ((unsigned)pb[1] << 16);
    pd.y = (unsigned)pb[2] | ((unsigned)pb[3] << 16);
    *(uint2*)(Ps + (wave*16 + c)*136 + mt*16 + g*4) = pd;
  }
  dv += __shfl_xor(dv, 16);
  dv += __shfl_xor(dv, 32);
  if (g == 0) dvl[wave*16 + c] = 1.f/dv;
  __syncthreads();

  // PV: og = P . ctxT^T, M=this wave's qrow tile, N=2 d-tiles, K=128
  #pragma unroll
  for (int n = 0; n < 2; n++){
    f32x4 acc = zz;
    #pragma unroll
    for (int kk = 0; kk < 4; kk++){
      bf16x8 ap = *(const bf16x8*)(Ps  + (wave*16 + c)*136 + kk*32 + g*8);
      bf16x8 bc = *(const bf16x8*)(ctl + (n*16 + c)*136    + kk*32 + g*8);
      acc = __builtin_amdgcn_mfma_f32_16x16x32_bf16(ap, bc, acc, 0, 0, 0);
    }
    #pragma unroll
    for (int r = 0; r < 4; r++){
      int qrow = wave*16 + g*4 + r;
      float val = acc[r]*dvl[qrow];
      o[(size_t)(b*NTOK + i0 + qrow)*C + h*DH + n*16 + c] = f2b(val);
    }
  }
}

// Local windowed attention via MFMA. One block per (b, head, window); 4 waves x 16 q-rows.
// S^T = K·Q^T (A=K rows, B=Q rows); softmax in-register (no stab: scores O(1));
// P -> LDS bf16; O^T = V^T·P^T (A=V^T rows, B=P rows). All LDS reads natural b128.
__global__ __launch_bounds__(256) void k_local2(const ushort* __restrict__ q, const ushort* __restrict__ k,
        const ushort* __restrict__ v, ushort* __restrict__ o){
  int blk = blockIdx.x;
  int w = blk & (NW-1);
  int rem = blk >> 7;
  int hl = rem & 7, b = rem >> 3;
  int hd = GH + hl;
  __shared__ __align__(16) ushort Ks[192*32];      // [key][d]        12.0KB
  __shared__ __align__(16) ushort Vt[32*200];      // [d][key] pad    12.5KB
  __shared__ __align__(16) ushort Ps[4*16*200];    // per-wave [q][key] pad 25KB
  int tid = threadIdx.x;
  int lane = tid & 63, wave = tid >> 6;
  int c = lane & 15, g = lane >> 4;

  const ushort* kbase = k + (size_t)b*NTOK*C + hd*DH;
  const ushort* vbase = v + (size_t)b*NTOK*C + hd*DH;
  // stage K linear [192][32] via global_load_lds (768 x 16B chunks)
  #pragma unroll
  for (int s = 0; s < 3; s++){
    int ch = tid + s*256;
    int row = ch >> 2, part = ch & 3;
    int kp = min(max((w-1)*WIN + row, 0), NTOK-1);
    gload16(kbase + (size_t)kp*C + part*8, (char*)Ks + (s*256 + wave*64)*16);
  }
  // stage V transposed [32][200]
  #pragma unroll
  for (int s = 0; s < 3; s++){
    int ch = tid + s*256;
    int row = ch >> 2, part = ch & 3;
    int kp = min(max((w-1)*WIN + row, 0), NTOK-1);
    uint4 vv = *(const uint4*)(vbase + (size_t)kp*C + part*8);
    const ushort* vp = (const ushort*)&vv;
    #pragma unroll
    for (int j = 0; j < 8; j++) Vt[(part*8+j)*200 + row] = vp[j];
  }
  // Q B-frag: lane holds Q[c][8g..8g+7] of this wave's 16 rows
  int qrow = w*WIN + wave*16 + c;
  bf16x8 qf = *(const bf16x8*)(q + ((size_t)b*NTOK + qrow)*C + hd*DH + g*8);
  asm volatile("s_waitcnt vmcnt(0)" ::: "memory");
  __syncthreads();

  f32x4 zz = {0.f, 0.f, 0.f, 0.f};
  f32x4 st[12];
  #pragma unroll
  for (int t = 0; t < 12; t++){
    bf16x8 af = *(const bf16x8*)(Ks + (16*t + c)*32 + g*8);
    st[t] = __builtin_amdgcn_mfma_f32_16x16x32_bf16(af, qf, zz, 0, 0, 0);
  }
  int t0 = (w == 0) ? 4 : 0;
  int t1 = (w == NW-1) ? 8 : 12;
  float lsum = 0.f;
  ushort* pw = Ps + wave*3200 + c*200;
  #pragma unroll
  for (int t = 0; t < 12; t++){
    bool valid = (t >= t0) && (t < t1);
    float p0 = valid ? __expf(st[t][0]*F_LSCALE) : 0.f;
    float p1 = valid ? __expf(st[t][1]*F_LSCALE) : 0.f;
    float p2 = valid ? __expf(st[t][2]*F_LSCALE) : 0.f;
    float p3 = valid ? __expf(st[t][3]*F_LSCALE) : 0.f;
    lsum += (p0+p1)+(p2+p3);
    uint2 pd;
    pd.x = (unsigned)f2b(p0) | ((unsigned)f2b(p1) << 16);
    pd.y = (unsigned)f2b(p2) | ((unsigned)f2b(p3) << 16);
    *(uint2*)(pw + 16*t + 4*g) = pd;
  }
  lsum += __shfl_xor(lsum, 16);
  lsum += __shfl_xor(lsum, 32);

  f32x4 oc0 = zz, oc1 = zz;
  #pragma unroll
  for (int kb = 0; kb < 6; kb++){
    bf16x8 pf = *(const bf16x8*)(pw + kb*32 + g*8);
    bf16x8 v0 = *(const bf16x8*)(Vt + c*200 + kb*32 + g*8);
    bf16x8 v1 = *(const bf16x8*)(Vt + (16 + c)*200 + kb*32 + g*8);
    oc0 = __builtin_amdgcn_mfma_f32_16x16x32_bf16(v0, pf, oc0, 0, 0, 0);
    oc1 = __builtin_amdgcn_mfma_f32_16x16x32_bf16(v1, pf, oc1, 0, 0, 0);
  }
  float inv = 1.f/lsum;
  ushort* orow = o + ((size_t)b*NTOK + qrow)*C + hd*DH;
  uint2 w0, w1;
  w0.x = (unsigned)f2b(oc0[0]*inv) | ((unsigned)f2b(oc0[1]*inv) << 16);
  w0.y = (unsigned)f2b(oc0[2]*inv) | ((unsigned)f2b(oc0[3]*inv) << 16);
  w1.x = (unsigned)f2b(oc1[0]*inv) | ((unsigned)f2b(oc1[1]*inv) << 16);
  w1.y = (unsigned)f2b(oc1[2]*inv) | ((unsigned)f2b(oc1[3]*inv) << 16);
  *(uint2*)(orow + 4*g)      = w0;
  *(uint2*)(orow + 16 + 4*g) = w1;
}

} // namespace

extern "C" void kernel_launch(void* const* d_in, const int* in_sizes, int n_in,
                              void* d_out, int out_size, void* d_ws, size_t ws_size,
                              hipStream_t stream){
  (void)in_sizes; (void)n_in; (void)out_size; (void)ws_size;
  const float* x     = (const float*)d_in[0];
  const float* ln1_g = (const float*)d_in[1];
  const float* ln1_b = (const float*)d_in[2];
  const float* Wq    = (const float*)d_in[3];
  const float* bq    = (const float*)d_in[4];
  const float* Wk    = (const float*)d_in[5];
  const float* bk    = (const float*)d_in[6];
  const float* Wv    = (const float*)d_in[7];
  const float* bv    = (const float*)d_in[8];
  const float* Wo    = (const float*)d_in[9];
  const float* bo    = (const float*)d_in[10];
  const float* proj  = (const float*)d_in[11];
  const float* ln2_g = (const float*)d_in[12];
  const float* ln2_b = (const float*)d_in[13];
  const float* W1    = (const float*)d_in[14];
  const float* b1    = (const float*)d_in[15];
  const float* W2    = (const float*)d_in[16];
  const float* b2    = (const float*)d_in[17];

  float* h = (float*)d_out;
  const size_t MC = (size_t)MROWS*C;
  char* w = (char*)d_ws;
  auto alloc = [&](size_t bytes)->char*{ char* p = w; w += (bytes + 255) & ~(size_t)255; return p; };

  ushort* y16  = (ushort*)alloc(MC*2);
  ushort* qb16 = (ushort*)alloc(MC*2);   // q,k,v contiguous: QKV-fused epilogue indexes bid*MC
  ushort* kb16 = (ushort*)alloc(MC*2);
  ushort* vb16 = (ushort*)alloc(MC*2);
  ushort* o16  = (ushort*)alloc(MC*2);
  ushort* wt   = (ushort*)alloc((size_t)2097152*2);   // per-layer transposed bf16 weights
  float*  cost = (float*) alloc((size_t)NTOK*16*4);
  float*  sint = (float*) alloc((size_t)NTOK*16*4);
  float*  diag = (float*) alloc((size_t)16*NTOK*4);
  float*  bmax = (float*) alloc(16*32*4);
  float*  stabf= (float*) alloc(16*4);
  float*  ctxb = (float*) alloc((size_t)16*NBF*DH*4);
  float*  ksum = (float*) alloc((size_t)16*NBF*4);

  ushort* mid16 = qb16;                    // FFN mid (M*FF bf16 = 32MB) aliases qb16+kb16 (dead)
  float*  ctxp  = (float*)o16;             // ctx partials (14.4MB) alias o16 (written later)
  float*  ksump = ctxp + (size_t)16*64*NBF*DH;

  ushort* wtq = wt;                        // wtq/wtk/wtv contiguous -> fused (1536,512) B^T
  ushort* wtk = wt +  262144;
  ushort* wtv = wt +  524288;
  ushort* wto = wt +  786432;
  ushort* wt1 = wt + 1048576;
  ushort* wt2 = wt + 1572864;

  k_tables<<<(NTOK*16 + 255)/256, 256, 0, stream>>>(cost, sint);
  k_copy<<<(int)((MC/4 + 255)/256), 256, 0, stream>>>((const float4*)x, (float4*)h, (int)(MC/4));

  dim3 blk(256);
  dim3 g512(4, 128);    // N=512
  dim3 gqkv(12, 128);   // N=1536 fused
  dim3 gff(8, 128);     // N=1024

  for (int l = 0; l < 2; l++){
    const float* pj = proj + (size_t)l*NBF*DH;
    k_wcvt<<<dim3(16,16), blk, 0, stream>>>(Wq + (size_t)l*C*C,  wtq, C, C);
    k_wcvt<<<dim3(16,16), blk, 0, stream>>>(Wk + (size_t)l*C*C,  wtk, C, C);
    k_wcvt<<<dim3(16,16), blk, 0, stream>>>(Wv + (size_t)l*C*C,  wtv, C, C);
    k_wcvt<<<dim3(16,16), blk, 0, stream>>>(Wo + (size_t)l*C*C,  wto, C, C);
    k_wcvt<<<dim3(32,16), blk, 0, stream>>>(W1 + (size_t)l*C*FF, wt1, C, FF);
    k_wcvt<<<dim3(16,32), blk, 0, stream>>>(W2 + (size_t)l*FF*C, wt2, FF, C);

    k_ln<<<MROWS, 256, 0, stream>>>(h, ln1_g + l*C, ln1_b + l*C, y16);
    k_mgemm<0,1,1><<<gqkv, blk, 0, stream>>>(y16, wtq, bq + l*C, bk + l*C, bv + l*C,
                                             nullptr, nullptr, qb16, cost, sint, 1536, C);
    k_kpre<<<16*32, 256, 0, stream>>>(kb16, pj, diag, bmax);
    k_redmax<<<16, 64, 0, stream>>>(bmax, stabf);
    k_ctx2<<<16*64, 128, 0, stream>>>(kb16, vb16, pj, diag, stabf, ctxp, ksump);
    k_ctxred<<<16*NBF, 64, 0, stream>>>(ctxp, ksump, ctxb, ksum);
    k_qattn3<<<16*128, 256, 0, stream>>>(qb16, pj, ctxb, ksum, o16);
    k_local2<<<BATCH*8*NW, 256, 0, stream>>>(qb16, kb16, vb16, o16);
    k_mgemm<0,0,0><<<g512, blk, 0, stream>>>(o16, wto, bo + l*C, nullptr, nullptr, h, h, nullptr,
                                             nullptr, nullptr, C, C);
    k_ln<<<MROWS, 256, 0, stream>>>(h, ln2_g + l*C, ln2_b + l*C, y16);
    k_mgemm<1,1,0><<<gff, blk, 0, stream>>>(y16, wt1, b1 + l*FF, nullptr, nullptr, nullptr,
                                            nullptr, mid16, nullptr, nullptr, FF, C);
    k_mgemm<0,0,0><<<g512, blk, 0, stream>>>(mid16, wt2, b2 + l*C, nullptr, nullptr, h, h, nullptr,
                                             nullptr, nullptr, C, FF);
  }
}

// Round 7
// 662.087 us; speedup vs baseline: 10.9606x; 1.2280x over previous
//
#include <hip/hip_runtime.h>
#include <math.h>

namespace {

constexpr int BATCH = 2;
constexpr int NTOK  = 8192;    // tokens per batch (T*H*W)
constexpr int MROWS = 16384;   // BATCH*NTOK
constexpr int C     = 512;
constexpr int GH    = 8;
constexpr int DH    = 32;
constexpr int WIN   = 64;
constexpr int NW    = 128;     // NTOK/WIN
constexpr int FF    = 1024;
constexpr int NBF   = 110;     // int(32*ln(32))
constexpr int NBFP  = 128;     // padded feature count (MFMA tiles)

constexpr float F_DN     = 0.42044820762685725f;   // 32^-0.25
constexpr float F_RNORM  = 0.09534625892455924f;   // 110^-0.5
constexpr float F_LSCALE = 0.17677669529663687f;   // 32^-0.5

typedef __attribute__((ext_vector_type(8))) short bf16x8;
typedef __attribute__((ext_vector_type(4))) float f32x4;

__device__ __forceinline__ ushort f2b(float f){
  unsigned u = __float_as_uint(f);
  unsigned r = u + 0x7FFFu + ((u >> 16) & 1u);
  return (ushort)(r >> 16);
}
__device__ __forceinline__ float b2f(ushort u){
  return __uint_as_float((unsigned)u << 16);
}
__device__ __forceinline__ void unpk(unsigned u, float& a, float& b){
  a = __uint_as_float(u << 16);
  b = __uint_as_float(u & 0xffff0000u);
}

__device__ __forceinline__ void gload16(const void* g, void* l){
  __builtin_amdgcn_global_load_lds((const __attribute__((address_space(1))) void*)g,
                                   (__attribute__((address_space(3))) void*)l, 16, 0, 0);
}

__global__ void k_tables(float* __restrict__ cost, float* __restrict__ sint){
  int idx = blockIdx.x*256 + threadIdx.x;
  if (idx >= NTOK*16) return;
  int pos = idx >> 4, f = idx & 15;
  float inv = powf(10000.f, -(float)f/16.f);
  float ang = (float)pos * inv;
  cost[idx] = cosf(ang);
  sint[idx] = sinf(ang);
}

__global__ void k_copy(const float4* __restrict__ s, float4* __restrict__ d, int n){
  int i = blockIdx.x*256 + threadIdx.x;
  if (i < n) d[i] = s[i];
}

// fp32 (K,N) -> bf16 transposed (N,K)
__global__ __launch_bounds__(256) void k_wcvt(const float* __restrict__ W, ushort* __restrict__ Wt,
                                              int K, int N){
  __shared__ float t[32][33];
  int bx = blockIdx.x, by = blockIdx.y;
  int tx = threadIdx.x & 31, ty = threadIdx.x >> 5;
  #pragma unroll
  for (int r = ty; r < 32; r += 8) t[r][tx] = W[(size_t)(by*32+r)*N + bx*32 + tx];
  __syncthreads();
  #pragma unroll
  for (int r = ty; r < 32; r += 8) Wt[(size_t)(bx*32+r)*K + by*32 + tx] = f2b(t[tx][r]);
}

__global__ __launch_bounds__(256) void k_ln(const float* __restrict__ x, const float* __restrict__ g,
                     const float* __restrict__ b, ushort* __restrict__ y){
  int row = blockIdx.x, t = threadIdx.x;
  const float* xr = x + (size_t)row*C;
  float2 v = *(const float2*)(xr + 2*t);
  float s = v.x + v.y, ss = v.x*v.x + v.y*v.y;
  #pragma unroll
  for (int o = 32; o; o >>= 1){ s += __shfl_down(s, o); ss += __shfl_down(ss, o); }
  __shared__ float rs[4], rss[4];
  int wv = t >> 6, ln = t & 63;
  if (ln == 0){ rs[wv] = s; rss[wv] = ss; }
  __syncthreads();
  float S = rs[0]+rs[1]+rs[2]+rs[3], SS = rss[0]+rss[1]+rss[2]+rss[3];
  float mean = S * (1.f/C);
  float var  = SS * (1.f/C) - mean*mean;
  float rstd = rsqrtf(var + 1e-5f);
  float2 gg = *(const float2*)(g + 2*t);
  float2 bb = *(const float2*)(b + 2*t);
  ushort2 ov;
  ov.x = f2b((v.x - mean)*rstd*gg.x + bb.x);
  ov.y = f2b((v.y - mean)*rstd*gg.y + bb.y);
  *(ushort2*)(y + (size_t)row*C + 2*t) = ov;
}

// bf16 MFMA GEMM, m97 structure: out = ACT(A@B + bias) (+res)
// A: (M,K) bf16 row-major.  Bt: (N,K) bf16 row-major (i.e. B^T).
// grid (Nd/128, M/128), 256 threads (4 waves, 2x2 of 64x64).
// QKV==1: Nd=1536 logical; output de-interleaved into 3 contiguous (M,512)
// buffers at outb + bid*MROWS*C, with RoPE fused for local-head cols of q,k.
template<int ACT, int OBF, int QKV>
__global__ __launch_bounds__(256) void k_mgemm(const ushort* __restrict__ A, const ushort* __restrict__ Bt,
      const float* __restrict__ bias, const float* __restrict__ bias2, const float* __restrict__ bias3,
      const float* __restrict__ res, float* __restrict__ outf, ushort* __restrict__ outb,
      const float* __restrict__ cosT, const float* __restrict__ sinT, int Nd, int Kd){
  __shared__ ushort As[128*32];
  __shared__ ushort Bs[128*32];
  int tid = threadIdx.x;
  int lane = tid & 63, wave = tid >> 6;
  int wr = wave >> 1, wc = wave & 1;
  int row0 = blockIdx.y*128, col0 = blockIdx.x*128;
  f32x4 acc[4][4] = {};
  for (int k0 = 0; k0 < Kd; k0 += 32){
    __syncthreads();
    #pragma unroll
    for (int c = 0; c < 2; c++){
      int off = (wave*2 + c)*1024 + lane*16;       // byte offset in 8KB tile
      int r = off >> 6, ke = (off & 63) >> 1;      // row, k-element
      gload16(A  + (size_t)(row0 + r)*Kd + k0 + ke, (char*)As + (wave*2 + c)*1024);
      gload16(Bt + (size_t)(col0 + r)*Kd + k0 + ke, (char*)Bs + (wave*2 + c)*1024);
    }
    __syncthreads();
    bf16x8 af[4], bfr[4];
    #pragma unroll
    for (int m = 0; m < 4; m++)
      af[m] = *(const bf16x8*)((const char*)As + (wr*64 + m*16 + (lane&15))*64 + (lane>>4)*16);
    #pragma unroll
    for (int n = 0; n < 4; n++)
      bfr[n] = *(const bf16x8*)((const char*)Bs + (wc*64 + n*16 + (lane&15))*64 + (lane>>4)*16);
    #pragma unroll
    for (int m = 0; m < 4; m++)
      #pragma unroll
      for (int n = 0; n < 4; n++)
        acc[m][n] = __builtin_amdgcn_mfma_f32_16x16x32_bf16(af[m], bfr[n], acc[m][n], 0, 0, 0);
  }
  if (QKV){
    // de-interleave into q/k/v + fused RoPE on local-head cols of q,k
    #pragma unroll
    for (int m = 0; m < 4; m++){
      int rbase = row0 + wr*64 + m*16 + (lane>>4)*4;
      #pragma unroll
      for (int np = 0; np < 2; np++){
        int n0 = 2*np, n1 = n0 + 1;
        int ccol = col0 + wc*64 + n0*16 + (lane&15);   // ccol&31 == lane&15 (<16)
        int bid = ccol >> 9;
        int cl  = ccol & 511;
        const float* bp = (bid == 0) ? bias : (bid == 1) ? bias2 : bias3;
        float b0 = bp[cl], b1 = bp[cl+16];
        bool dorope = (bid < 2) && (cl >= 256);
        ushort* obase = outb + (size_t)bid*MROWS*C;
        int d = lane & 15;
        #pragma unroll
        for (int r = 0; r < 4; r++){
          int grow = rbase + r;
          float a  = acc[m][n0][r] + b0;
          float bb = acc[m][n1][r] + b1;
          if (dorope){
            int pos = grow & (NTOK-1);
            float cv = cosT[pos*16 + d], sv = sinT[pos*16 + d];
            float na = a*cv - bb*sv;
            float nb = bb*cv + a*sv;
            a = na; bb = nb;
          }
          obase[(size_t)grow*C + cl]      = f2b(a);
          obase[(size_t)grow*C + cl + 16] = f2b(bb);
        }
      }
    }
    return;
  }
  #pragma unroll
  for (int m = 0; m < 4; m++){
    int rbase = row0 + wr*64 + m*16 + (lane>>4)*4;
    #pragma unroll
    for (int n = 0; n < 4; n++){
      int ccol = col0 + wc*64 + n*16 + (lane&15);
      float bv = bias[ccol];
      #pragma unroll
      for (int r = 0; r < 4; r++){
        int grow = rbase + r;
        float vv = acc[m][n][r] + bv;
        if (ACT == 1) vv = 0.5f*vv*(1.f + erff(vv*0.7071067811865476f));
        if (res) vv += res[(size_t)grow*Nd + ccol];
        if (OBF) outb[(size_t)grow*Nd + ccol] = f2b(vv);
        else     outf[(size_t)grow*Nd + ccol] = vv;
      }
    }
  }
}

// Performer K pre-pass: per-row diag + per-(bh,chunk) max of dd. No atomics.
__global__ __launch_bounds__(256) void k_kpre(const ushort* __restrict__ k, const float* __restrict__ proj,
        float* __restrict__ diag, float* __restrict__ bmax){
  int bh = blockIdx.x >> 5, chunk = blockIdx.x & 31;
  int b = bh >> 3, h = bh & 7;
  __shared__ float pl[NBF][DH];
  int t = threadIdx.x;
  for (int idx = t; idx < NBF*DH; idx += 256) pl[idx>>5][idx&31] = proj[idx]*F_DN;
  __syncthreads();
  int i = chunk*256 + t;
  const ushort* kr = k + (size_t)(b*NTOK + i)*C + h*DH;
  ushort kt[32];
  *(uint4*)(kt)    = *(const uint4*)(kr);
  *(uint4*)(kt+8)  = *(const uint4*)(kr+8);
  *(uint4*)(kt+16) = *(const uint4*)(kr+16);
  *(uint4*)(kt+24) = *(const uint4*)(kr+24);
  float kv[DH];
  #pragma unroll
  for (int d = 0; d < DH; d++) kv[d] = b2f(kt[d]);
  float sq = 0.f;
  #pragma unroll
  for (int d = 0; d < DH; d++) sq += kv[d]*kv[d];
  diag[bh*NTOK + i] = 0.5f*F_DN*F_DN*sq;
  float mx = -1e30f;
  for (int m = 0; m < NBF; m++){
    float a = 0.f;
    #pragma unroll
    for (int d = 0; d < DH; d++) a += kv[d]*pl[m][d];
    mx = fmaxf(mx, a);
  }
  #pragma unroll
  for (int o = 32; o; o >>= 1) mx = fmaxf(mx, __shfl_down(mx, o));
  __shared__ float red[4];
  if ((t & 63) == 0) red[t>>6] = mx;
  __syncthreads();
  if (t == 0) bmax[bh*32 + chunk] = fmaxf(fmaxf(red[0],red[1]), fmaxf(red[2],red[3]));
}

__global__ void k_redmax(const float* __restrict__ bmax, float* __restrict__ stabf){
  int bh = blockIdx.x, t = threadIdx.x;
  float v = (t < 32) ? bmax[bh*32 + t] : -1e30f;
  #pragma unroll
  for (int o = 32; o; o >>= 1) v = fmaxf(v, __shfl_down(v, o));
  if (t == 0) stabf[bh] = v;
}

// Performer K side v3 (MFMA). Block = (bh, 256 k-rows); 4 waves; 4 slices of 64 rows.
// QK: S[krow][feat] = K·proj^T — wave w owns krow tile w; A-frag = K rows (global),
// B-frag = proj rows (LDS). kp = rnorm*(exp(dd-diag-stab)+1e-4), masked feat<NBF.
// P[feat][krow] bf16 LDS (packed uint2 writes). V^T staged [48][72] with ones-row at
// d=32 (ksum falls out of the PV MFMA) and zero rows 33..47.
// PV: ctx[feat][d] += P·V — wave w owns feat tiles {2w,2w+1}, N tiles {0,1,2}; acc in regs.
__global__ __launch_bounds__(256) void k_ctx3(const ushort* __restrict__ k, const ushort* __restrict__ v,
        const float* __restrict__ proj, const float* __restrict__ diag, const float* __restrict__ stabf,
        float* __restrict__ ctxp, float* __restrict__ ksump){
  int bh = blockIdx.x >> 5, chunk = blockIdx.x & 31;
  int b = bh >> 3, h = bh & 7;
  __shared__ __align__(16) ushort pl[NBFP*40];   // proj bf16 [feat][40 pad]  10.0KB
  __shared__ __align__(16) ushort Ps[NBFP*72];   // P [feat][64+8 pad]        18.0KB
  __shared__ __align__(16) ushort Vt[48*72];     // V^T slice [48][72]         6.75KB
  __shared__ float dgl[256];
  int tid = threadIdx.x;
  int lane = tid & 63, wave = tid >> 6;
  int c = lane & 15, g = lane >> 4;
  int i0 = chunk*256;

  for (int idx = tid; idx < NBFP*32; idx += 256){
    int f = idx >> 5, d = idx & 31;
    pl[f*40 + d] = (f < NBF) ? f2b(proj[f*32 + d]*F_DN) : (ushort)0;
  }
  dgl[tid] = diag[bh*NTOK + i0 + tid];
  for (int idx = tid; idx < 15*72; idx += 256) Vt[33*72 + idx] = 0;   // zero rows 33..47
  float stab_v = stabf[bh];

  const ushort* kbase = k + ((size_t)b*NTOK + i0)*C + h*DH;
  const ushort* vbase = v + ((size_t)b*NTOK + i0)*C + h*DH;
  f32x4 zz = {0.f, 0.f, 0.f, 0.f};
  f32x4 acc[2][3] = {};

  for (int s = 0; s < 4; s++){
    __syncthreads();     // Ps/Vt free (also covers pl/dgl init at s=0)
    // stage V^T slice + ones row
    {
      int r = tid >> 2, part = tid & 3;
      uint4 vv = *(const uint4*)(vbase + (size_t)(s*64 + r)*C + part*8);
      const ushort* vp = (const ushort*)&vv;
      #pragma unroll
      for (int j = 0; j < 8; j++) Vt[(part*8+j)*72 + r] = vp[j];
      if (tid < 64) Vt[32*72 + tid] = 0x3F80;   // bf16 1.0
    }
    // QK + kp + P write
    bf16x8 af = *(const bf16x8*)(kbase + (size_t)(s*64 + wave*16 + c)*C + g*8);
    #pragma unroll
    for (int ft = 0; ft < 8; ft++){
      bf16x8 bf = *(const bf16x8*)(pl + (ft*16 + c)*40 + g*8);
      f32x4 dd = __builtin_amdgcn_mfma_f32_16x16x32_bf16(af, bf, zz, 0, 0, 0);
      int feat = ft*16 + c;
      bool fvalid = feat < NBF;
      ushort pb[4];
      #pragma unroll
      for (int r = 0; r < 4; r++){
        float kp = 0.f;
        if (fvalid){
          float dg_ = dgl[s*64 + wave*16 + g*4 + r];
          kp = F_RNORM*(__expf(dd[r] - dg_ - stab_v) + 1e-4f);
        }
        pb[r] = f2b(kp);
      }
      uint2 pd;
      pd.x = (unsigned)pb[0] | ((unsigned)pb[1] << 16);
      pd.y = (unsigned)pb[2] | ((unsigned)pb[3] << 16);
      *(uint2*)(Ps + (ft*16 + c)*72 + wave*16 + g*4) = pd;
    }
    __syncthreads();
    // PV accumulate
    #pragma unroll
    for (int i = 0; i < 2; i++){
      int ft = wave*2 + i;
      #pragma unroll
      for (int kk = 0; kk < 2; kk++){
        bf16x8 ap = *(const bf16x8*)(Ps + (ft*16 + c)*72 + kk*32 + g*8);
        #pragma unroll
        for (int nt = 0; nt < 3; nt++){
          bf16x8 bv = *(const bf16x8*)(Vt + (nt*16 + c)*72 + kk*32 + g*8);
          acc[i][nt] = __builtin_amdgcn_mfma_f32_16x16x32_bf16(ap, bv, acc[i][nt], 0, 0, 0);
        }
      }
    }
  }
  // write partials: ctx[feat][d] (nt 0,1) + ksum (nt 2, d==32 -> c==0)
  size_t pbase = (size_t)(bh*32 + chunk)*NBF;
  #pragma unroll
  for (int i = 0; i < 2; i++){
    int ftb = (wave*2 + i)*16;
    #pragma unroll
    for (int r = 0; r < 4; r++){
      int feat = ftb + g*4 + r;
      if (feat < NBF){
        #pragma unroll
        for (int nt = 0; nt < 2; nt++)
          ctxp[(pbase + feat)*DH + nt*16 + c] = acc[i][nt][r];
        if (c == 0) ksump[pbase + feat] = acc[i][2][r];
      }
    }
  }
}

__global__ void k_ctxred(const float* __restrict__ ctxp, const float* __restrict__ ksump,
                         float* __restrict__ ctx, float* __restrict__ ksum){
  int bh = blockIdx.x / NBF, m = blockIdx.x % NBF;
  int t = threadIdx.x;
  if (t < DH){
    float s = 0.f;
    for (int c = 0; c < 32; c++) s += ctxp[((size_t)(bh*32 + c)*NBF + m)*DH + t];
    ctx[((size_t)bh*NBF + m)*DH + t] = s;
  } else if (t == DH){
    float s = 0.f;
    for (int c = 0; c < 32; c++) s += ksump[(size_t)(bh*32 + c)*NBF + m];
    ksum[bh*NBF + m] = s;
  }
}

// Performer Q side v3 (MFMA). One block per (bh, 64 q-rows); 4 waves, wave w owns q-rows 16w..16w+15.
__global__ __launch_bounds__(256) void k_qattn3(const ushort* __restrict__ q, const float* __restrict__ proj,
        const float* __restrict__ ctx, const float* __restrict__ ksum, ushort* __restrict__ o){
  int bh = blockIdx.x >> 7, chunk = blockIdx.x & 127;
  int b = bh >> 3, h = bh & 7;
  __shared__ __align__(16) ushort pl[NBFP*40];    // proj bf16 [feat][40 pad]   10.0KB
  __shared__ __align__(16) ushort ql[64*40];      // Q [qrow][40 pad]            5.0KB
  __shared__ __align__(16) ushort ctl[32*136];    // ctx^T [d][136 pad]          8.5KB
  __shared__ __align__(16) ushort Ps[64*136];     // P [qrow][136 pad]          17.0KB
  __shared__ float ksl[NBFP];
  __shared__ float dgl[64];
  __shared__ float dvl[64];
  int tid = threadIdx.x;
  int lane = tid & 63, wave = tid >> 6;
  int c = lane & 15, g = lane >> 4;
  int i0 = chunk*64;

  for (int idx = tid; idx < NBFP*32; idx += 256){
    int f = idx >> 5, d = idx & 31;
    pl[f*40 + d] = (f < NBF) ? f2b(proj[f*32 + d]*F_DN) : (ushort)0;
  }
  {
    int row = tid >> 2, part = tid & 3;
    uint4 qq = *(const uint4*)(q + (size_t)(b*NTOK + i0 + row)*C + h*DH + part*8);
    *(uint4*)(ql + row*40 + part*8) = qq;
    const ushort* qp_ = (const ushort*)&qq;
    float sq = 0.f;
    #pragma unroll
    for (int j = 0; j < 8; j++){ float vv = b2f(qp_[j]); sq += vv*vv; }
    sq += __shfl_xor(sq, 1);
    sq += __shfl_xor(sq, 2);
    if (part == 0) dgl[row] = 0.5f*F_DN*F_DN*sq;
  }
  for (int idx = tid; idx < 32*NBFP; idx += 256){
    int d = idx >> 7, f = idx & 127;
    float vv = (f < NBF) ? ctx[((size_t)bh*NBF + f)*DH + d] : 0.f;
    ctl[d*136 + f] = f2b(vv);
  }
  if (tid < NBFP) ksl[tid] = (tid < NBF) ? ksum[bh*NBF + tid] : 0.f;
  __syncthreads();

  f32x4 zz = {0.f, 0.f, 0.f, 0.f};
  bf16x8 qf = *(const bf16x8*)(ql + (wave*16 + c)*40 + g*8);
  f32x4 st[8];
  #pragma unroll
  for (int mt = 0; mt < 8; mt++){
    bf16x8 af = *(const bf16x8*)(pl + (mt*16 + c)*40 + g*8);
    st[mt] = __builtin_amdgcn_mfma_f32_16x16x32_bf16(af, qf, zz, 0, 0, 0);
  }
  float mx = -1e30f;
  #pragma unroll
  for (int mt = 0; mt < 8; mt++)
    #pragma unroll
    for (int r = 0; r < 4; r++){
      int feat = mt*16 + g*4 + r;
      if (feat < NBF) mx = fmaxf(mx, st[mt][r]);
    }
  mx = fmaxf(mx, __shfl_xor(mx, 16));
  mx = fmaxf(mx, __shfl_xor(mx, 32));
  float diagv = dgl[wave*16 + c];
  float dv = 0.f;
  #pragma unroll
  for (int mt = 0; mt < 8; mt++){
    ushort pb[4];
    #pragma unroll
    for (int r = 0; r < 4; r++){
      int feat = mt*16 + g*4 + r;
      float qp = 0.f;
      if (feat < NBF) qp = F_RNORM*(__expf(st[mt][r] - diagv - mx) + 1e-4f);
      ushort qb = f2b(qp);
      pb[r] = qb;
      dv += b2f(qb)*ksl[feat];
    }
    uint2 pd;
    pd.x = (unsigned)pb[0] | ((unsigned)pb[1] << 16);
    pd.y = (unsigned)pb[2] | ((unsigned)pb[3] << 16);
    *(uint2*)(Ps + (wave*16 + c)*136 + mt*16 + g*4) = pd;
  }
  dv += __shfl_xor(dv, 16);
  dv += __shfl_xor(dv, 32);
  if (g == 0) dvl[wave*16 + c] = 1.f/dv;
  __syncthreads();

  #pragma unroll
  for (int n = 0; n < 2; n++){
    f32x4 acc = zz;
    #pragma unroll
    for (int kk = 0; kk < 4; kk++){
      bf16x8 ap = *(const bf16x8*)(Ps  + (wave*16 + c)*136 + kk*32 + g*8);
      bf16x8 bc = *(const bf16x8*)(ctl + (n*16 + c)*136    + kk*32 + g*8);
      acc = __builtin_amdgcn_mfma_f32_16x16x32_bf16(ap, bc, acc, 0, 0, 0);
    }
    #pragma unroll
    for (int r = 0; r < 4; r++){
      int qrow = wave*16 + g*4 + r;
      float val = acc[r]*dvl[qrow];
      o[(size_t)(b*NTOK + i0 + qrow)*C + h*DH + n*16 + c] = f2b(val);
    }
  }
}

// Local windowed attention via MFMA. One block per (b, head, window); 4 waves x 16 q-rows.
__global__ __launch_bounds__(256) void k_local2(const ushort* __restrict__ q, const ushort* __restrict__ k,
        const ushort* __restrict__ v, ushort* __restrict__ o){
  int blk = blockIdx.x;
  int w = blk & (NW-1);
  int rem = blk >> 7;
  int hl = rem & 7, b = rem >> 3;
  int hd = GH + hl;
  __shared__ __align__(16) ushort Ks[192*32];      // [key][d]        12.0KB
  __shared__ __align__(16) ushort Vt[32*200];      // [d][key] pad    12.5KB
  __shared__ __align__(16) ushort Ps[4*16*200];    // per-wave [q][key] pad 25KB
  int tid = threadIdx.x;
  int lane = tid & 63, wave = tid >> 6;
  int c = lane & 15, g = lane >> 4;

  const ushort* kbase = k + (size_t)b*NTOK*C + hd*DH;
  const ushort* vbase = v + (size_t)b*NTOK*C + hd*DH;
  #pragma unroll
  for (int s = 0; s < 3; s++){
    int ch = tid + s*256;
    int row = ch >> 2, part = ch & 3;
    int kp = min(max((w-1)*WIN + row, 0), NTOK-1);
    gload16(kbase + (size_t)kp*C + part*8, (char*)Ks + (s*256 + wave*64)*16);
  }
  #pragma unroll
  for (int s = 0; s < 3; s++){
    int ch = tid + s*256;
    int row = ch >> 2, part = ch & 3;
    int kp = min(max((w-1)*WIN + row, 0), NTOK-1);
    uint4 vv = *(const uint4*)(vbase + (size_t)kp*C + part*8);
    const ushort* vp = (const ushort*)&vv;
    #pragma unroll
    for (int j = 0; j < 8; j++) Vt[(part*8+j)*200 + row] = vp[j];
  }
  int qrow = w*WIN + wave*16 + c;
  bf16x8 qf = *(const bf16x8*)(q + ((size_t)b*NTOK + qrow)*C + hd*DH + g*8);
  asm volatile("s_waitcnt vmcnt(0)" ::: "memory");
  __syncthreads();

  f32x4 zz = {0.f, 0.f, 0.f, 0.f};
  f32x4 st[12];
  #pragma unroll
  for (int t = 0; t < 12; t++){
    bf16x8 af = *(const bf16x8*)(Ks + (16*t + c)*32 + g*8);
    st[t] = __builtin_amdgcn_mfma_f32_16x16x32_bf16(af, qf, zz, 0, 0, 0);
  }
  int t0 = (w == 0) ? 4 : 0;
  int t1 = (w == NW-1) ? 8 : 12;
  float lsum = 0.f;
  ushort* pw = Ps + wave*3200 + c*200;
  #pragma unroll
  for (int t = 0; t < 12; t++){
    bool valid = (t >= t0) && (t < t1);
    float p0 = valid ? __expf(st[t][0]*F_LSCALE) : 0.f;
    float p1 = valid ? __expf(st[t][1]*F_LSCALE) : 0.f;
    float p2 = valid ? __expf(st[t][2]*F_LSCALE) : 0.f;
    float p3 = valid ? __expf(st[t][3]*F_LSCALE) : 0.f;
    lsum += (p0+p1)+(p2+p3);
    uint2 pd;
    pd.x = (unsigned)f2b(p0) | ((unsigned)f2b(p1) << 16);
    pd.y = (unsigned)f2b(p2) | ((unsigned)f2b(p3) << 16);
    *(uint2*)(pw + 16*t + 4*g) = pd;
  }
  lsum += __shfl_xor(lsum, 16);
  lsum += __shfl_xor(lsum, 32);

  f32x4 oc0 = zz, oc1 = zz;
  #pragma unroll
  for (int kb = 0; kb < 6; kb++){
    bf16x8 pf = *(const bf16x8*)(pw + kb*32 + g*8);
    bf16x8 v0 = *(const bf16x8*)(Vt + c*200 + kb*32 + g*8);
    bf16x8 v1 = *(const bf16x8*)(Vt + (16 + c)*200 + kb*32 + g*8);
    oc0 = __builtin_amdgcn_mfma_f32_16x16x32_bf16(v0, pf, oc0, 0, 0, 0);
    oc1 = __builtin_amdgcn_mfma_f32_16x16x32_bf16(v1, pf, oc1, 0, 0, 0);
  }
  float inv = 1.f/lsum;
  ushort* orow = o + ((size_t)b*NTOK + qrow)*C + hd*DH;
  uint2 w0, w1;
  w0.x = (unsigned)f2b(oc0[0]*inv) | ((unsigned)f2b(oc0[1]*inv) << 16);
  w0.y = (unsigned)f2b(oc0[2]*inv) | ((unsigned)f2b(oc0[3]*inv) << 16);
  w1.x = (unsigned)f2b(oc1[0]*inv) | ((unsigned)f2b(oc1[1]*inv) << 16);
  w1.y = (unsigned)f2b(oc1[2]*inv) | ((unsigned)f2b(oc1[3]*inv) << 16);
  *(uint2*)(orow + 4*g)      = w0;
  *(uint2*)(orow + 16 + 4*g) = w1;
}

} // namespace

extern "C" void kernel_launch(void* const* d_in, const int* in_sizes, int n_in,
                              void* d_out, int out_size, void* d_ws, size_t ws_size,
                              hipStream_t stream){
  (void)in_sizes; (void)n_in; (void)out_size; (void)ws_size;
  const float* x     = (const float*)d_in[0];
  const float* ln1_g = (const float*)d_in[1];
  const float* ln1_b = (const float*)d_in[2];
  const float* Wq    = (const float*)d_in[3];
  const float* bq    = (const float*)d_in[4];
  const float* Wk    = (const float*)d_in[5];
  const float* bk    = (const float*)d_in[6];
  const float* Wv    = (const float*)d_in[7];
  const float* bv    = (const float*)d_in[8];
  const float* Wo    = (const float*)d_in[9];
  const float* bo    = (const float*)d_in[10];
  const float* proj  = (const float*)d_in[11];
  const float* ln2_g = (const float*)d_in[12];
  const float* ln2_b = (const float*)d_in[13];
  const float* W1    = (const float*)d_in[14];
  const float* b1    = (const float*)d_in[15];
  const float* W2    = (const float*)d_in[16];
  const float* b2    = (const float*)d_in[17];

  float* h = (float*)d_out;
  const size_t MC = (size_t)MROWS*C;
  char* w = (char*)d_ws;
  auto alloc = [&](size_t bytes)->char*{ char* p = w; w += (bytes + 255) & ~(size_t)255; return p; };

  ushort* y16  = (ushort*)alloc(MC*2);
  ushort* qb16 = (ushort*)alloc(MC*2);   // q,k,v contiguous: QKV-fused epilogue indexes bid*MC
  ushort* kb16 = (ushort*)alloc(MC*2);
  ushort* vb16 = (ushort*)alloc(MC*2);
  ushort* o16  = (ushort*)alloc(MC*2);
  ushort* wt   = (ushort*)alloc((size_t)2097152*2);   // per-layer transposed bf16 weights
  float*  cost = (float*) alloc((size_t)NTOK*16*4);
  float*  sint = (float*) alloc((size_t)NTOK*16*4);
  float*  diag = (float*) alloc((size_t)16*NTOK*4);
  float*  bmax = (float*) alloc(16*32*4);
  float*  stabf= (float*) alloc(16*4);
  float*  ctxb = (float*) alloc((size_t)16*NBF*DH*4);
  float*  ksum = (float*) alloc((size_t)16*NBF*4);

  ushort* mid16 = qb16;                    // FFN mid (M*FF bf16 = 32MB) aliases qb16+kb16 (dead)
  float*  ctxp  = (float*)o16;             // ctx partials (7.2MB) alias o16 (written later)
  float*  ksump = ctxp + (size_t)16*32*NBF*DH;

  ushort* wtq = wt;                        // wtq/wtk/wtv contiguous -> fused (1536,512) B^T
  ushort* wtk = wt +  262144;
  ushort* wtv = wt +  524288;
  ushort* wto = wt +  786432;
  ushort* wt1 = wt + 1048576;
  ushort* wt2 = wt + 1572864;

  k_tables<<<(NTOK*16 + 255)/256, 256, 0, stream>>>(cost, sint);
  k_copy<<<(int)((MC/4 + 255)/256), 256, 0, stream>>>((const float4*)x, (float4*)h, (int)(MC/4));

  dim3 blk(256);
  dim3 g512(4, 128);    // N=512
  dim3 gqkv(12, 128);   // N=1536 fused
  dim3 gff(8, 128);     // N=1024

  for (int l = 0; l < 2; l++){
    const float* pj = proj + (size_t)l*NBF*DH;
    k_wcvt<<<dim3(16,16), blk, 0, stream>>>(Wq + (size_t)l*C*C,  wtq, C, C);
    k_wcvt<<<dim3(16,16), blk, 0, stream>>>(Wk + (size_t)l*C*C,  wtk, C, C);
    k_wcvt<<<dim3(16,16), blk, 0, stream>>>(Wv + (size_t)l*C*C,  wtv, C, C);
    k_wcvt<<<dim3(16,16), blk, 0, stream>>>(Wo + (size_t)l*C*C,  wto, C, C);
    k_wcvt<<<dim3(32,16), blk, 0, stream>>>(W1 + (size_t)l*C*FF, wt1, C, FF);
    k_wcvt<<<dim3(16,32), blk, 0, stream>>>(W2 + (size_t)l*FF*C, wt2, FF, C);

    k_ln<<<MROWS, 256, 0, stream>>>(h, ln1_g + l*C, ln1_b + l*C, y16);
    k_mgemm<0,1,1><<<gqkv, blk, 0, stream>>>(y16, wtq, bq + l*C, bk + l*C, bv + l*C,
                                             nullptr, nullptr, qb16, cost, sint, 1536, C);
    k_kpre<<<16*32, 256, 0, stream>>>(kb16, pj, diag, bmax);
    k_redmax<<<16, 64, 0, stream>>>(bmax, stabf);
    k_ctx3<<<16*32, 256, 0, stream>>>(kb16, vb16, pj, diag, stabf, ctxp, ksump);
    k_ctxred<<<16*NBF, 64, 0, stream>>>(ctxp, ksump, ctxb, ksum);
    k_qattn3<<<16*128, 256, 0, stream>>>(qb16, pj, ctxb, ksum, o16);
    k_local2<<<BATCH*8*NW, 256, 0, stream>>>(qb16, kb16, vb16, o16);
    k_mgemm<0,0,0><<<g512, blk, 0, stream>>>(o16, wto, bo + l*C, nullptr, nullptr, h, h, nullptr,
                                             nullptr, nullptr, C, C);
    k_ln<<<MROWS, 256, 0, stream>>>(h, ln2_g + l*C, ln2_b + l*C, y16);
    k_mgemm<1,1,0><<<gff, blk, 0, stream>>>(y16, wt1, b1 + l*FF, nullptr, nullptr, nullptr,
                                            nullptr, mid16, nullptr, nullptr, FF, C);
    k_mgemm<0,0,0><<<g512, blk, 0, stream>>>(mid16, wt2, b2 + l*C, nullptr, nullptr, h, h, nullptr,
                                             nullptr, nullptr, C, FF);
  }
}